// Round 1
// baseline (1737.736 us; speedup 1.0000x reference)
//
#include <hip/hip_runtime.h>
#include <hip/hip_bf16.h>
#include <math.h>

#define B_ 32
#define L_ 720
#define N_ 512
#define H_ 16
#define D_ 64
#define TOPK_ 8

// ---------------------------------------------------------------------------
// Kernel 1: Q/K projections, sim = Q@K^T (diag masked), top-8 per row,
// softmax over the 8 vals. grid = N_ blocks (one per row n), 512 threads.
// ---------------------------------------------------------------------------
__global__ __launch_bounds__(512) void topk_kernel(
    const float* __restrict__ ve,   // (N,H)
    const float* __restrict__ Wq, const float* __restrict__ bq,
    const float* __restrict__ Wk, const float* __restrict__ bk,
    float* __restrict__ w_out,      // (N,TOPK)
    int*   __restrict__ idx_out)    // (N,TOPK)
{
    const int nrow = blockIdx.x;
    const int t = threadIdx.x;

    __shared__ float Ksh[N_ * 17];   // stride 17 to dodge bank conflicts
    __shared__ float qrow[H_];
    __shared__ float sim[N_];
    __shared__ float rv[N_];
    __shared__ int   ri[N_];
    __shared__ float selv[TOPK_];
    __shared__ int   seli[TOPK_];

    // K[t][h] for all t
    {
        float vrow[H_];
        #pragma unroll
        for (int j = 0; j < H_; j++) vrow[j] = ve[t * H_ + j];
        #pragma unroll
        for (int h = 0; h < H_; h++) {
            float acc = bk[h];
            #pragma unroll
            for (int j = 0; j < H_; j++) acc += vrow[j] * Wk[j * H_ + h];
            Ksh[t * 17 + h] = acc;
        }
    }
    // Q[nrow][h]
    if (t < H_) {
        float acc = bq[t];
        #pragma unroll
        for (int j = 0; j < H_; j++) acc += ve[nrow * H_ + j] * Wq[j * H_ + t];
        qrow[t] = acc;
    }
    __syncthreads();

    // sim row
    {
        float acc = 0.f;
        #pragma unroll
        for (int h = 0; h < H_; h++) acc += qrow[h] * Ksh[t * 17 + h];
        sim[t] = (t == nrow) ? -1e9f : acc;
    }
    __syncthreads();

    // top-8: iterative argmax (tie -> lowest index, matches jax.lax.top_k)
    for (int k = 0; k < TOPK_; k++) {
        rv[t] = sim[t]; ri[t] = t;
        __syncthreads();
        for (int s2 = 256; s2 > 0; s2 >>= 1) {
            if (t < s2) {
                float v2 = rv[t + s2]; int i2 = ri[t + s2];
                if (v2 > rv[t] || (v2 == rv[t] && i2 < ri[t])) { rv[t] = v2; ri[t] = i2; }
            }
            __syncthreads();
        }
        if (t == 0) {
            selv[k] = rv[0]; seli[k] = ri[0];
            sim[ri[0]] = -INFINITY;
        }
        __syncthreads();
    }

    if (t == 0) {
        float vmax = selv[0];            // descending -> first is max
        float esum = 0.f, ev[TOPK_];
        #pragma unroll
        for (int k = 0; k < TOPK_; k++) { ev[k] = expf(selv[k] - vmax); esum += ev[k]; }
        float inv = 1.f / esum;
        #pragma unroll
        for (int k = 0; k < TOPK_; k++) {
            w_out[nrow * TOPK_ + k] = ev[k] * inv;
            idx_out[nrow * TOPK_ + k] = seli[k];
        }
    }
}

// ---------------------------------------------------------------------------
// Kernel 2: s[b,l] = x[b,l,:]·Wscore + bscore. grid = B*L blocks, 64 threads.
// ---------------------------------------------------------------------------
__global__ __launch_bounds__(64) void score_kernel(
    const float* __restrict__ x, const float* __restrict__ Wscore,
    const float* __restrict__ bscore, float* __restrict__ s)
{
    const int row = blockIdx.x;
    const int t = threadIdx.x;
    const float* xr = x + (size_t)row * N_;
    float acc = 0.f;
    for (int n = t; n < N_; n += 64) acc += xr[n] * Wscore[n];
    for (int off = 32; off > 0; off >>= 1) acc += __shfl_down(acc, off);
    if (t == 0) s[row] = acc + bscore[0];
}

// ---------------------------------------------------------------------------
// Kernel 3: softmax over L per batch, in place. grid = B blocks, 256 threads.
// ---------------------------------------------------------------------------
__global__ __launch_bounds__(256) void attn_softmax_kernel(float* __restrict__ s)
{
    const int b = blockIdx.x;
    const int t = threadIdx.x;
    float* row = s + (size_t)b * L_;

    __shared__ float sm[4];
    __shared__ float sm2[4];

    float lmax = -1e30f;
    for (int l = t; l < L_; l += 256) lmax = fmaxf(lmax, row[l]);
    for (int off = 32; off > 0; off >>= 1) lmax = fmaxf(lmax, __shfl_down(lmax, off));
    if ((t & 63) == 0) sm[t >> 6] = lmax;
    __syncthreads();
    float gmax = fmaxf(fmaxf(sm[0], sm[1]), fmaxf(sm[2], sm[3]));

    float lsum = 0.f;
    for (int l = t; l < L_; l += 256) {
        float e = expf(row[l] - gmax);
        row[l] = e;
        lsum += e;
    }
    for (int off = 32; off > 0; off >>= 1) lsum += __shfl_down(lsum, off);
    if ((t & 63) == 0) sm2[t >> 6] = lsum;
    __syncthreads();
    float inv = 1.f / (sm2[0] + sm2[1] + sm2[2] + sm2[3]);
    for (int l = t; l < L_; l += 256) row[l] *= inv;
}

// ---------------------------------------------------------------------------
// Kernel 4: center_raw[b,n] = sum_l attn[b,l]*x[b,l,n]. grid = B, 512 threads.
// ---------------------------------------------------------------------------
__global__ __launch_bounds__(512) void center_raw_kernel(
    const float* __restrict__ x, const float* __restrict__ attn,
    float* __restrict__ craw)
{
    const int b = blockIdx.x;
    const int n = threadIdx.x;
    __shared__ float ash[L_];
    for (int l = n; l < L_; l += 512) ash[l] = attn[b * L_ + l];
    __syncthreads();
    const float* xb = x + (size_t)b * L_ * N_;
    float acc = 0.f;
    for (int l = 0; l < L_; l++) acc += ash[l] * xb[(size_t)l * N_ + n];
    craw[b * N_ + n] = acc;
}

__device__ __forceinline__ float gelu_exact(float v) {
    return 0.5f * v * (1.0f + erff(v * 0.70710678118654752440f));
}

// ---------------------------------------------------------------------------
// Kernel 5: center MLP + precompute cg[b,n] = center[b]·Wg[512:,n] + bg[n].
// grid = B blocks, 512 threads.
// ---------------------------------------------------------------------------
__global__ __launch_bounds__(512) void center_mlp_kernel(
    const float* __restrict__ craw,
    const float* __restrict__ Wc1, const float* __restrict__ bc1,
    const float* __restrict__ Wc2, const float* __restrict__ bc2,
    const float* __restrict__ Wcn, const float* __restrict__ bcn,
    const float* __restrict__ Wg,  const float* __restrict__ bg,
    float* __restrict__ center, float* __restrict__ cg)
{
    const int b = blockIdx.x;
    const int t = threadIdx.x;
    __shared__ float cr[N_];
    __shared__ float h1[D_];
    __shared__ float h2[D_];
    __shared__ float cent[N_];

    cr[t] = craw[b * N_ + t];
    __syncthreads();
    if (t < D_) {
        float acc = bc1[t];
        for (int m = 0; m < N_; m++) acc += cr[m] * Wc1[m * D_ + t];
        h1[t] = gelu_exact(acc);
    }
    __syncthreads();
    if (t < D_) {
        float acc = bc2[t];
        #pragma unroll 8
        for (int j = 0; j < D_; j++) acc += h1[j] * Wc2[j * D_ + t];
        h2[t] = gelu_exact(acc);
    }
    __syncthreads();
    {
        float acc = bcn[t];
        #pragma unroll 8
        for (int j = 0; j < D_; j++) acc += h2[j] * Wcn[j * N_ + t];
        center[b * N_ + t] = acc;
        cent[t] = acc;
    }
    __syncthreads();
    {
        float acc = bg[t];
        const float* p = Wg + (size_t)N_ * N_ + t;  // rows 512..1023, column t
        #pragma unroll 4
        for (int m = 0; m < N_; m++) { acc += cent[m] * p[0]; p += N_; }
        cg[b * N_ + t] = acc;
    }
}

// ---------------------------------------------------------------------------
// Kernel 6 (HOT): per-row ring gather + gate matmul + fuse + Wf matmul +
// residual + LayerNorm. grid = B*L blocks, 512 threads.
// ---------------------------------------------------------------------------
__global__ __launch_bounds__(512) void fuse_kernel(
    const float* __restrict__ x,
    const float* __restrict__ w,   const int* __restrict__ idx,
    const float* __restrict__ center, const float* __restrict__ cg,
    const float* __restrict__ Wg,  const float* __restrict__ Wf,
    const float* __restrict__ bfv,
    const float* __restrict__ gamma, const float* __restrict__ beta,
    float* __restrict__ out)
{
    const int row = blockIdx.x;          // b*L + l
    const int b = row / L_;
    const int n = threadIdx.x;

    __shared__ float xrow[N_];
    __shared__ float ring[N_];
    __shared__ float fus[N_];
    __shared__ float rs[8], rq[8];

    const float* xr = x + (size_t)row * N_;
    xrow[n] = xr[n];
    __syncthreads();

    // ring_out[b,l,n] = sum_k w[n,k] * x[b,l,idx[n,k]]
    float r = 0.f;
    #pragma unroll
    for (int k = 0; k < TOPK_; k++)
        r += w[n * TOPK_ + k] * xrow[idx[n * TOPK_ + k]];
    ring[n] = r;
    __syncthreads();

    // gate = sigmoid(ring·Wg[:512,n] + cg[b,n])
    float g = cg[b * N_ + n];
    {
        const float* p = Wg + n;
        #pragma unroll 4
        for (int m = 0; m < N_; m++) { g += ring[m] * p[0]; p += N_; }
    }
    g = 1.f / (1.f + expf(-g));
    float f = g * r + (1.f - g) * center[b * N_ + n];
    fus[n] = f;
    __syncthreads();

    // h = fused·Wf[:,n] + bf[n] + x[b,l,n]
    float h = bfv[n] + xrow[n];
    {
        const float* p = Wf + n;
        #pragma unroll 4
        for (int m = 0; m < N_; m++) { h += fus[m] * p[0]; p += N_; }
    }

    // LayerNorm over n
    float sum = h, sq = h * h;
    for (int off = 32; off > 0; off >>= 1) {
        sum += __shfl_down(sum, off);
        sq  += __shfl_down(sq,  off);
    }
    const int wid = n >> 6;
    if ((n & 63) == 0) { rs[wid] = sum; rq[wid] = sq; }
    __syncthreads();
    if (n == 0) {
        float S = 0.f, Q2 = 0.f;
        #pragma unroll
        for (int i = 0; i < 8; i++) { S += rs[i]; Q2 += rq[i]; }
        rs[0] = S; rq[0] = Q2;
    }
    __syncthreads();
    const float mu  = rs[0] * (1.0f / N_);
    const float var = rq[0] * (1.0f / N_) - mu * mu;
    const float inv = 1.0f / sqrtf(var + 1e-5f);
    out[(size_t)row * N_ + n] = (h - mu) * inv * gamma[n] + beta[n];
}

// ---------------------------------------------------------------------------
extern "C" void kernel_launch(void* const* d_in, const int* in_sizes, int n_in,
                              void* d_out, int out_size, void* d_ws, size_t ws_size,
                              hipStream_t stream) {
    const float* x       = (const float*)d_in[0];
    const float* ve      = (const float*)d_in[1];
    const float* Wq      = (const float*)d_in[2];
    const float* bq      = (const float*)d_in[3];
    const float* Wk      = (const float*)d_in[4];
    const float* bk      = (const float*)d_in[5];
    const float* Wscore  = (const float*)d_in[6];
    const float* bscore  = (const float*)d_in[7];
    const float* Wc1     = (const float*)d_in[8];
    const float* bc1     = (const float*)d_in[9];
    const float* Wc2     = (const float*)d_in[10];
    const float* bc2     = (const float*)d_in[11];
    const float* Wcn     = (const float*)d_in[12];
    const float* bcn     = (const float*)d_in[13];
    const float* Wg      = (const float*)d_in[14];
    const float* bg      = (const float*)d_in[15];
    const float* Wf      = (const float*)d_in[16];
    const float* bf      = (const float*)d_in[17];
    const float* gamma   = (const float*)d_in[18];
    const float* beta    = (const float*)d_in[19];
    float* out = (float*)d_out;

    char* p = (char*)d_ws;
    float* ws_w    = (float*)p; p += N_ * TOPK_ * sizeof(float);
    int*   ws_idx  = (int*)p;   p += N_ * TOPK_ * sizeof(int);
    float* ws_s    = (float*)p; p += B_ * L_ * sizeof(float);
    float* ws_craw = (float*)p; p += B_ * N_ * sizeof(float);
    float* ws_cent = (float*)p; p += B_ * N_ * sizeof(float);
    float* ws_cg   = (float*)p; p += B_ * N_ * sizeof(float);

    topk_kernel<<<N_, 512, 0, stream>>>(ve, Wq, bq, Wk, bk, ws_w, ws_idx);
    score_kernel<<<B_ * L_, 64, 0, stream>>>(x, Wscore, bscore, ws_s);
    attn_softmax_kernel<<<B_, 256, 0, stream>>>(ws_s);
    center_raw_kernel<<<B_, 512, 0, stream>>>(x, ws_s, ws_craw);
    center_mlp_kernel<<<B_, 512, 0, stream>>>(ws_craw, Wc1, bc1, Wc2, bc2,
                                              Wcn, bcn, Wg, bg, ws_cent, ws_cg);
    fuse_kernel<<<B_ * L_, 512, 0, stream>>>(x, ws_w, ws_idx, ws_cent, ws_cg,
                                             Wg, Wf, bf, gamma, beta, out);
}

// Round 2
// 458.399 us; speedup vs baseline: 3.7909x; 3.7909x over previous
//
#include <hip/hip_runtime.h>
#include <hip/hip_bf16.h>
#include <math.h>

#define B_ 32
#define L_ 720
#define N_ 512
#define H_ 16
#define D_ 64
#define TOPK_ 8
#define M_ (B_ * L_)          // 23040 rows
#define MTILE 64              // rows per GEMM block
#define GEMM_BLOCKS (M_ / MTILE)  // 360

typedef __bf16 bf16x8 __attribute__((ext_vector_type(8)));
typedef float f32x16 __attribute__((ext_vector_type(16)));

// ---------------------------------------------------------------------------
// Kernel 1: Q/K projections, sim = Q@K^T (diag masked), top-8 per row,
// softmax over the 8 vals. grid = N_ blocks, 512 threads.
// ---------------------------------------------------------------------------
__global__ __launch_bounds__(512) void topk_kernel(
    const float* __restrict__ ve,
    const float* __restrict__ Wq, const float* __restrict__ bq,
    const float* __restrict__ Wk, const float* __restrict__ bk,
    float* __restrict__ w_out, int* __restrict__ idx_out)
{
    const int nrow = blockIdx.x;
    const int t = threadIdx.x;

    __shared__ float Ksh[N_ * 17];
    __shared__ float qrow[H_];
    __shared__ float sim[N_];
    __shared__ float rv[N_];
    __shared__ int   ri[N_];
    __shared__ float selv[TOPK_];
    __shared__ int   seli[TOPK_];

    {
        float vrow[H_];
        #pragma unroll
        for (int j = 0; j < H_; j++) vrow[j] = ve[t * H_ + j];
        #pragma unroll
        for (int h = 0; h < H_; h++) {
            float acc = bk[h];
            #pragma unroll
            for (int j = 0; j < H_; j++) acc += vrow[j] * Wk[j * H_ + h];
            Ksh[t * 17 + h] = acc;
        }
    }
    if (t < H_) {
        float acc = bq[t];
        #pragma unroll
        for (int j = 0; j < H_; j++) acc += ve[nrow * H_ + j] * Wq[j * H_ + t];
        qrow[t] = acc;
    }
    __syncthreads();

    {
        float acc = 0.f;
        #pragma unroll
        for (int h = 0; h < H_; h++) acc += qrow[h] * Ksh[t * 17 + h];
        sim[t] = (t == nrow) ? -1e9f : acc;
    }
    __syncthreads();

    for (int k = 0; k < TOPK_; k++) {
        rv[t] = sim[t]; ri[t] = t;
        __syncthreads();
        for (int s2 = 256; s2 > 0; s2 >>= 1) {
            if (t < s2) {
                float v2 = rv[t + s2]; int i2 = ri[t + s2];
                if (v2 > rv[t] || (v2 == rv[t] && i2 < ri[t])) { rv[t] = v2; ri[t] = i2; }
            }
            __syncthreads();
        }
        if (t == 0) {
            selv[k] = rv[0]; seli[k] = ri[0];
            sim[ri[0]] = -INFINITY;
        }
        __syncthreads();
    }

    if (t == 0) {
        float vmax = selv[0];
        float esum = 0.f, ev[TOPK_];
        #pragma unroll
        for (int k = 0; k < TOPK_; k++) { ev[k] = expf(selv[k] - vmax); esum += ev[k]; }
        float inv = 1.f / esum;
        #pragma unroll
        for (int k = 0; k < TOPK_; k++) {
            w_out[nrow * TOPK_ + k] = ev[k] * inv;
            idx_out[nrow * TOPK_ + k] = seli[k];
        }
    }
}

// ---------------------------------------------------------------------------
// Kernel 2: s[b,l] = x[b,l,:]·Wscore + bscore
// ---------------------------------------------------------------------------
__global__ __launch_bounds__(64) void score_kernel(
    const float* __restrict__ x, const float* __restrict__ Wscore,
    const float* __restrict__ bscore, float* __restrict__ s)
{
    const int row = blockIdx.x;
    const int t = threadIdx.x;
    const float* xr = x + (size_t)row * N_;
    float acc = 0.f;
    for (int n = t; n < N_; n += 64) acc += xr[n] * Wscore[n];
    for (int off = 32; off > 0; off >>= 1) acc += __shfl_down(acc, off);
    if (t == 0) s[row] = acc + bscore[0];
}

// ---------------------------------------------------------------------------
// Kernel 3: softmax over L per batch
// ---------------------------------------------------------------------------
__global__ __launch_bounds__(256) void attn_softmax_kernel(float* __restrict__ s)
{
    const int b = blockIdx.x;
    const int t = threadIdx.x;
    float* row = s + (size_t)b * L_;

    __shared__ float sm[4];
    __shared__ float sm2[4];

    float lmax = -1e30f;
    for (int l = t; l < L_; l += 256) lmax = fmaxf(lmax, row[l]);
    for (int off = 32; off > 0; off >>= 1) lmax = fmaxf(lmax, __shfl_down(lmax, off));
    if ((t & 63) == 0) sm[t >> 6] = lmax;
    __syncthreads();
    float gmax = fmaxf(fmaxf(sm[0], sm[1]), fmaxf(sm[2], sm[3]));

    float lsum = 0.f;
    for (int l = t; l < L_; l += 256) {
        float e = expf(row[l] - gmax);
        row[l] = e;
        lsum += e;
    }
    for (int off = 32; off > 0; off >>= 1) lsum += __shfl_down(lsum, off);
    if ((t & 63) == 0) sm2[t >> 6] = lsum;
    __syncthreads();
    float inv = 1.f / (sm2[0] + sm2[1] + sm2[2] + sm2[3]);
    for (int l = t; l < L_; l += 256) row[l] *= inv;
}

// ---------------------------------------------------------------------------
// Kernel 4: center_raw[b,n] = sum_l attn[b,l]*x[b,l,n]
// ---------------------------------------------------------------------------
__global__ __launch_bounds__(512) void center_raw_kernel(
    const float* __restrict__ x, const float* __restrict__ attn,
    float* __restrict__ craw)
{
    const int b = blockIdx.x;
    const int n = threadIdx.x;
    __shared__ float ash[L_];
    for (int l = n; l < L_; l += 512) ash[l] = attn[b * L_ + l];
    __syncthreads();
    const float* xb = x + (size_t)b * L_ * N_;
    float acc = 0.f;
    for (int l = 0; l < L_; l++) acc += ash[l] * xb[(size_t)l * N_ + n];
    craw[b * N_ + n] = acc;
}

__device__ __forceinline__ float gelu_exact(float v) {
    return 0.5f * v * (1.0f + erff(v * 0.70710678118654752440f));
}

// ---------------------------------------------------------------------------
// Kernel 5: center MLP + cg[b,n] = center[b]·Wg[512:,n] + bg[n]  (fp32)
// ---------------------------------------------------------------------------
__global__ __launch_bounds__(512) void center_mlp_kernel(
    const float* __restrict__ craw,
    const float* __restrict__ Wc1, const float* __restrict__ bc1,
    const float* __restrict__ Wc2, const float* __restrict__ bc2,
    const float* __restrict__ Wcn, const float* __restrict__ bcn,
    const float* __restrict__ Wg,  const float* __restrict__ bg,
    float* __restrict__ center, float* __restrict__ cg)
{
    const int b = blockIdx.x;
    const int t = threadIdx.x;
    __shared__ float cr[N_];
    __shared__ float h1[D_];
    __shared__ float h2[D_];
    __shared__ float cent[N_];

    cr[t] = craw[b * N_ + t];
    __syncthreads();
    if (t < D_) {
        float acc = bc1[t];
        for (int m = 0; m < N_; m++) acc += cr[m] * Wc1[m * D_ + t];
        h1[t] = gelu_exact(acc);
    }
    __syncthreads();
    if (t < D_) {
        float acc = bc2[t];
        #pragma unroll 8
        for (int j = 0; j < D_; j++) acc += h1[j] * Wc2[j * D_ + t];
        h2[t] = gelu_exact(acc);
    }
    __syncthreads();
    {
        float acc = bcn[t];
        #pragma unroll 8
        for (int j = 0; j < D_; j++) acc += h2[j] * Wcn[j * N_ + t];
        center[b * N_ + t] = acc;
        cent[t] = acc;
    }
    __syncthreads();
    {
        float acc = bg[t];
        const float* p = Wg + (size_t)N_ * N_ + t;
        #pragma unroll 4
        for (int m = 0; m < N_; m++) { acc += cent[m] * p[0]; p += N_; }
        cg[b * N_ + t] = acc;
    }
}

// ---------------------------------------------------------------------------
// Kernel 6: transpose+convert weights to bf16. blocks 0..511 -> WgT (top half
// of Wg), 512..1023 -> WfT. WgT[n][k] = Wg[k][n].
// ---------------------------------------------------------------------------
__global__ __launch_bounds__(256) void convert_kernel(
    const float* __restrict__ Wg, const float* __restrict__ Wf,
    __hip_bfloat16* __restrict__ WgT, __hip_bfloat16* __restrict__ WfT)
{
    const int n = blockIdx.x & 511;
    const bool isf = blockIdx.x >= 512;
    const float* src = isf ? Wf : Wg;
    __hip_bfloat16* dst = isf ? WfT : WgT;
    for (int k = threadIdx.x; k < N_; k += 256)
        dst[n * N_ + k] = __float2bfloat16(src[(size_t)k * N_ + n]);
}

// ---------------------------------------------------------------------------
// Kernel 7: ring gather -> bf16 A matrix. 8 rows/block, 512 threads.
// ring[row,n] = sum_k w[n,k] * x[row, idx[n,k]]
// ---------------------------------------------------------------------------
#define RPB 8
__global__ __launch_bounds__(512) void ring_kernel(
    const float* __restrict__ x, const float* __restrict__ w,
    const int* __restrict__ idx, __hip_bfloat16* __restrict__ ring)
{
    __shared__ float xs[RPB][N_];
    __shared__ float wsh[N_ * TOPK_];
    __shared__ int   ish[N_ * TOPK_];
    const int t = threadIdx.x;
    const int row0 = blockIdx.x * RPB;

    for (int i = t; i < N_ * TOPK_; i += 512) { wsh[i] = w[i]; ish[i] = idx[i]; }
    for (int i = t; i < RPB * N_; i += 512) {
        int r = i >> 9, c = i & 511;
        xs[r][c] = x[(size_t)(row0 + r) * N_ + c];
    }
    __syncthreads();
    #pragma unroll
    for (int r = 0; r < RPB; ++r) {
        float acc = 0.f;
        #pragma unroll
        for (int k = 0; k < TOPK_; ++k)
            acc += wsh[t * TOPK_ + k] * xs[r][ish[t * TOPK_ + k]];
        ring[(size_t)(row0 + r) * N_ + t] = __float2bfloat16(acc);
    }
}

// ---------------------------------------------------------------------------
// GEMM core: C(64 x 512) = A_tile(64 x 512) @ BT^T, bf16 MFMA 32x32x16.
// Block: 256 threads = 4 waves, each wave owns a 128-col slice.
// LDS: Ash 64x(32+8), Bsh 512x(32+8), stride 40 bf16 (80B, 16B-aligned rows).
// ---------------------------------------------------------------------------
#define LSTR 40

// Kernel 8: gate GEMM. logits = ring @ WgT^T + cg; fused = g*ring+(1-g)*center
__global__ __launch_bounds__(256) void gemm_gate_kernel(
    const __hip_bfloat16* __restrict__ A,    // ring (M,512) bf16
    const __hip_bfloat16* __restrict__ BT,   // WgT (512,512) bf16
    const float* __restrict__ cg,            // (B,512)
    const float* __restrict__ center,        // (B,512)
    __hip_bfloat16* __restrict__ fused)      // (M,512) bf16
{
    __shared__ __hip_bfloat16 Ash[MTILE * LSTR];
    __shared__ __hip_bfloat16 Bsh[N_ * LSTR];
    const int tid  = threadIdx.x;
    const int lane = tid & 63;
    const int wv   = tid >> 6;
    const int m32  = lane & 31;
    const int half = lane >> 5;
    const int row0 = blockIdx.x * MTILE;

    f32x16 acc[2][4];
    #pragma unroll
    for (int i = 0; i < 2; i++)
        #pragma unroll
        for (int j = 0; j < 4; j++)
            #pragma unroll
            for (int e = 0; e < 16; e++) acc[i][j][e] = 0.f;

    for (int step = 0; step < 16; ++step) {
        const int k0 = step * 32;
        __syncthreads();
        {   // stage A: 64 rows x 32 el = 256 chunks of 16B
            int r = tid >> 2, seg = tid & 3;
            uint4 v = *(const uint4*)(A + (size_t)(row0 + r) * N_ + k0 + seg * 8);
            *(uint4*)(Ash + r * LSTR + seg * 8) = v;
        }
        #pragma unroll
        for (int i = 0; i < 8; ++i) {  // stage B: 512 rows x 32 el = 2048 chunks
            int id = tid + i * 256;
            int r = id >> 2, seg = id & 3;
            uint4 v = *(const uint4*)(BT + (size_t)r * N_ + k0 + seg * 8);
            *(uint4*)(Bsh + r * LSTR + seg * 8) = v;
        }
        __syncthreads();
        #pragma unroll
        for (int kh = 0; kh < 2; ++kh) {
            bf16x8 a0 = *(const bf16x8*)(Ash + m32 * LSTR        + kh * 16 + half * 8);
            bf16x8 a1 = *(const bf16x8*)(Ash + (32 + m32) * LSTR + kh * 16 + half * 8);
            #pragma unroll
            for (int ns = 0; ns < 4; ++ns) {
                const int n = wv * 128 + ns * 32 + m32;
                bf16x8 b = *(const bf16x8*)(Bsh + n * LSTR + kh * 16 + half * 8);
                acc[0][ns] = __builtin_amdgcn_mfma_f32_32x32x16_bf16(a0, b, acc[0][ns], 0, 0, 0);
                acc[1][ns] = __builtin_amdgcn_mfma_f32_32x32x16_bf16(a1, b, acc[1][ns], 0, 0, 0);
            }
        }
    }
    // epilogue: sigmoid gate + fuse
    #pragma unroll
    for (int ms = 0; ms < 2; ++ms)
        #pragma unroll
        for (int ns = 0; ns < 4; ++ns)
            #pragma unroll
            for (int reg = 0; reg < 16; ++reg) {
                int rl  = ms * 32 + (reg & 3) + 8 * (reg >> 2) + 4 * half;
                int rg  = row0 + rl;
                int col = wv * 128 + ns * 32 + m32;
                int b   = rg / L_;
                float logit = acc[ms][ns][reg] + cg[b * N_ + col];
                float g = 1.f / (1.f + expf(-logit));
                float rv = __bfloat162float(A[(size_t)rg * N_ + col]);
                float f = g * rv + (1.f - g) * center[b * N_ + col];
                fused[(size_t)rg * N_ + col] = __float2bfloat16(f);
            }
}

// Kernel 9: output GEMM. h = fused @ WfT^T + bf + x  (fp32 to d_out)
__global__ __launch_bounds__(256) void gemm_out_kernel(
    const __hip_bfloat16* __restrict__ A,    // fused (M,512) bf16
    const __hip_bfloat16* __restrict__ BT,   // WfT (512,512) bf16
    const float* __restrict__ x,
    const float* __restrict__ bfv,
    float* __restrict__ out)
{
    __shared__ __hip_bfloat16 Ash[MTILE * LSTR];
    __shared__ __hip_bfloat16 Bsh[N_ * LSTR];
    const int tid  = threadIdx.x;
    const int lane = tid & 63;
    const int wv   = tid >> 6;
    const int m32  = lane & 31;
    const int half = lane >> 5;
    const int row0 = blockIdx.x * MTILE;

    f32x16 acc[2][4];
    #pragma unroll
    for (int i = 0; i < 2; i++)
        #pragma unroll
        for (int j = 0; j < 4; j++)
            #pragma unroll
            for (int e = 0; e < 16; e++) acc[i][j][e] = 0.f;

    for (int step = 0; step < 16; ++step) {
        const int k0 = step * 32;
        __syncthreads();
        {
            int r = tid >> 2, seg = tid & 3;
            uint4 v = *(const uint4*)(A + (size_t)(row0 + r) * N_ + k0 + seg * 8);
            *(uint4*)(Ash + r * LSTR + seg * 8) = v;
        }
        #pragma unroll
        for (int i = 0; i < 8; ++i) {
            int id = tid + i * 256;
            int r = id >> 2, seg = id & 3;
            uint4 v = *(const uint4*)(BT + (size_t)r * N_ + k0 + seg * 8);
            *(uint4*)(Bsh + r * LSTR + seg * 8) = v;
        }
        __syncthreads();
        #pragma unroll
        for (int kh = 0; kh < 2; ++kh) {
            bf16x8 a0 = *(const bf16x8*)(Ash + m32 * LSTR        + kh * 16 + half * 8);
            bf16x8 a1 = *(const bf16x8*)(Ash + (32 + m32) * LSTR + kh * 16 + half * 8);
            #pragma unroll
            for (int ns = 0; ns < 4; ++ns) {
                const int n = wv * 128 + ns * 32 + m32;
                bf16x8 b = *(const bf16x8*)(Bsh + n * LSTR + kh * 16 + half * 8);
                acc[0][ns] = __builtin_amdgcn_mfma_f32_32x32x16_bf16(a0, b, acc[0][ns], 0, 0, 0);
                acc[1][ns] = __builtin_amdgcn_mfma_f32_32x32x16_bf16(a1, b, acc[1][ns], 0, 0, 0);
            }
        }
    }
    #pragma unroll
    for (int ms = 0; ms < 2; ++ms)
        #pragma unroll
        for (int ns = 0; ns < 4; ++ns)
            #pragma unroll
            for (int reg = 0; reg < 16; ++reg) {
                int rl  = ms * 32 + (reg & 3) + 8 * (reg >> 2) + 4 * half;
                int rg  = row0 + rl;
                int col = wv * 128 + ns * 32 + m32;
                float h = acc[ms][ns][reg] + bfv[col] + x[(size_t)rg * N_ + col];
                out[(size_t)rg * N_ + col] = h;
            }
}

// ---------------------------------------------------------------------------
// Kernel 10: in-place LayerNorm over rows of out. grid = M_, 512 threads.
// ---------------------------------------------------------------------------
__global__ __launch_bounds__(512) void ln_kernel(
    float* __restrict__ out,
    const float* __restrict__ gamma, const float* __restrict__ beta)
{
    const int row = blockIdx.x;
    const int n = threadIdx.x;
    __shared__ float rs[8], rq[8];

    float h = out[(size_t)row * N_ + n];
    float sum = h, sq = h * h;
    for (int off = 32; off > 0; off >>= 1) {
        sum += __shfl_down(sum, off);
        sq  += __shfl_down(sq,  off);
    }
    if ((n & 63) == 0) { rs[n >> 6] = sum; rq[n >> 6] = sq; }
    __syncthreads();
    if (n == 0) {
        float S = 0.f, Q2 = 0.f;
        #pragma unroll
        for (int i = 0; i < 8; i++) { S += rs[i]; Q2 += rq[i]; }
        rs[0] = S; rq[0] = Q2;
    }
    __syncthreads();
    const float mu  = rs[0] * (1.0f / N_);
    const float var = rq[0] * (1.0f / N_) - mu * mu;
    const float inv = 1.0f / sqrtf(var + 1e-5f);
    out[(size_t)row * N_ + n] = (h - mu) * inv * gamma[n] + beta[n];
}

// ---------------------------------------------------------------------------
extern "C" void kernel_launch(void* const* d_in, const int* in_sizes, int n_in,
                              void* d_out, int out_size, void* d_ws, size_t ws_size,
                              hipStream_t stream) {
    const float* x       = (const float*)d_in[0];
    const float* ve      = (const float*)d_in[1];
    const float* Wq      = (const float*)d_in[2];
    const float* bq      = (const float*)d_in[3];
    const float* Wk      = (const float*)d_in[4];
    const float* bk      = (const float*)d_in[5];
    const float* Wscore  = (const float*)d_in[6];
    const float* bscore  = (const float*)d_in[7];
    const float* Wc1     = (const float*)d_in[8];
    const float* bc1     = (const float*)d_in[9];
    const float* Wc2     = (const float*)d_in[10];
    const float* bc2     = (const float*)d_in[11];
    const float* Wcn     = (const float*)d_in[12];
    const float* bcn     = (const float*)d_in[13];
    const float* Wg      = (const float*)d_in[14];
    const float* bg      = (const float*)d_in[15];
    const float* Wf      = (const float*)d_in[16];
    const float* bf      = (const float*)d_in[17];
    const float* gamma   = (const float*)d_in[18];
    const float* beta    = (const float*)d_in[19];
    float* out = (float*)d_out;

    char* p = (char*)d_ws;
    float* ws_w    = (float*)p; p += N_ * TOPK_ * sizeof(float);
    int*   ws_idx  = (int*)p;   p += N_ * TOPK_ * sizeof(int);
    float* ws_s    = (float*)p; p += B_ * L_ * sizeof(float);
    float* ws_craw = (float*)p; p += B_ * N_ * sizeof(float);
    float* ws_cent = (float*)p; p += B_ * N_ * sizeof(float);
    float* ws_cg   = (float*)p; p += B_ * N_ * sizeof(float);
    __hip_bfloat16* ws_ring  = (__hip_bfloat16*)p; p += (size_t)M_ * N_ * sizeof(__hip_bfloat16);
    __hip_bfloat16* ws_fused = (__hip_bfloat16*)p; p += (size_t)M_ * N_ * sizeof(__hip_bfloat16);
    __hip_bfloat16* ws_WgT   = (__hip_bfloat16*)p; p += (size_t)N_ * N_ * sizeof(__hip_bfloat16);
    __hip_bfloat16* ws_WfT   = (__hip_bfloat16*)p; p += (size_t)N_ * N_ * sizeof(__hip_bfloat16);

    topk_kernel<<<N_, 512, 0, stream>>>(ve, Wq, bq, Wk, bk, ws_w, ws_idx);
    score_kernel<<<B_ * L_, 64, 0, stream>>>(x, Wscore, bscore, ws_s);
    attn_softmax_kernel<<<B_, 256, 0, stream>>>(ws_s);
    center_raw_kernel<<<B_, 512, 0, stream>>>(x, ws_s, ws_craw);
    center_mlp_kernel<<<B_, 512, 0, stream>>>(ws_craw, Wc1, bc1, Wc2, bc2,
                                              Wcn, bcn, Wg, bg, ws_cent, ws_cg);
    convert_kernel<<<1024, 256, 0, stream>>>(Wg, Wf, ws_WgT, ws_WfT);
    ring_kernel<<<M_ / RPB, 512, 0, stream>>>(x, ws_w, ws_idx, ws_ring);
    gemm_gate_kernel<<<GEMM_BLOCKS, 256, 0, stream>>>(ws_ring, ws_WgT, ws_cg,
                                                      ws_cent, ws_fused);
    gemm_out_kernel<<<GEMM_BLOCKS, 256, 0, stream>>>(ws_fused, ws_WfT, x, bf, out);
    ln_kernel<<<M_, 512, 0, stream>>>(out, gamma, beta);
}

// Round 3
// 338.846 us; speedup vs baseline: 5.1284x; 1.3528x over previous
//
#include <hip/hip_runtime.h>
#include <hip/hip_bf16.h>
#include <math.h>

#define B_ 32
#define L_ 720
#define N_ 512
#define H_ 16
#define D_ 64
#define TOPK_ 8
#define M_ (B_ * L_)          // 23040 rows
#define RPB 8                 // rows per ring block

typedef __bf16 bf16x8 __attribute__((ext_vector_type(8)));
typedef float f32x16 __attribute__((ext_vector_type(16)));

// ---------------------------------------------------------------------------
// async 16B global -> LDS (dest = wave-uniform lds base + lane*16)
// ---------------------------------------------------------------------------
__device__ __forceinline__ void async_cp16(const __hip_bfloat16* g, __hip_bfloat16* l) {
    __builtin_amdgcn_global_load_lds(
        (const __attribute__((address_space(1))) void*)g,
        (__attribute__((address_space(3))) void*)l, 16, 0, 0);
}

// fragment read from swizzled tile: tile rows of 64 bf16 (8 chunks of 16B),
// chunk j0 of row stored at position j0 ^ (row&7)
__device__ __forceinline__ bf16x8 frag_ld(const __hip_bfloat16* base, int row, int j0) {
    return *(const bf16x8*)(base + row * 64 + (((j0) ^ (row & 7)) << 3));
}

// ---------------------------------------------------------------------------
// Kernel 1: Q/K projections, sim, top-8, softmax(top-8). grid N_, 512 thr.
// ---------------------------------------------------------------------------
__global__ __launch_bounds__(512) void topk_kernel(
    const float* __restrict__ ve,
    const float* __restrict__ Wq, const float* __restrict__ bq,
    const float* __restrict__ Wk, const float* __restrict__ bk,
    float* __restrict__ w_out, int* __restrict__ idx_out)
{
    const int nrow = blockIdx.x;
    const int t = threadIdx.x;

    __shared__ float Ksh[N_ * 17];
    __shared__ float qrow[H_];
    __shared__ float sim[N_];
    __shared__ float rv[N_];
    __shared__ int   ri[N_];
    __shared__ float selv[TOPK_];
    __shared__ int   seli[TOPK_];

    {
        float vrow[H_];
        #pragma unroll
        for (int j = 0; j < H_; j++) vrow[j] = ve[t * H_ + j];
        #pragma unroll
        for (int h = 0; h < H_; h++) {
            float acc = bk[h];
            #pragma unroll
            for (int j = 0; j < H_; j++) acc += vrow[j] * Wk[j * H_ + h];
            Ksh[t * 17 + h] = acc;
        }
    }
    if (t < H_) {
        float acc = bq[t];
        #pragma unroll
        for (int j = 0; j < H_; j++) acc += ve[nrow * H_ + j] * Wq[j * H_ + t];
        qrow[t] = acc;
    }
    __syncthreads();

    {
        float acc = 0.f;
        #pragma unroll
        for (int h = 0; h < H_; h++) acc += qrow[h] * Ksh[t * 17 + h];
        sim[t] = (t == nrow) ? -1e9f : acc;
    }
    __syncthreads();

    for (int k = 0; k < TOPK_; k++) {
        rv[t] = sim[t]; ri[t] = t;
        __syncthreads();
        for (int s2 = 256; s2 > 0; s2 >>= 1) {
            if (t < s2) {
                float v2 = rv[t + s2]; int i2 = ri[t + s2];
                if (v2 > rv[t] || (v2 == rv[t] && i2 < ri[t])) { rv[t] = v2; ri[t] = i2; }
            }
            __syncthreads();
        }
        if (t == 0) {
            selv[k] = rv[0]; seli[k] = ri[0];
            sim[ri[0]] = -INFINITY;
        }
        __syncthreads();
    }

    if (t == 0) {
        float vmax = selv[0];
        float esum = 0.f, ev[TOPK_];
        #pragma unroll
        for (int k = 0; k < TOPK_; k++) { ev[k] = expf(selv[k] - vmax); esum += ev[k]; }
        float inv = 1.f / esum;
        #pragma unroll
        for (int k = 0; k < TOPK_; k++) {
            w_out[nrow * TOPK_ + k] = ev[k] * inv;
            idx_out[nrow * TOPK_ + k] = seli[k];
        }
    }
}

// ---------------------------------------------------------------------------
// Kernel 2: ring gather -> bf16 A matrix, FUSED with score s = x·Wscore+b.
// 8 rows/block, 512 threads = 8 waves (wave w owns row w's score).
// ---------------------------------------------------------------------------
__global__ __launch_bounds__(512) void ring_kernel(
    const float* __restrict__ x, const float* __restrict__ w,
    const int* __restrict__ idx,
    const float* __restrict__ Wscore, const float* __restrict__ bscore,
    __hip_bfloat16* __restrict__ ring, float* __restrict__ s)
{
    __shared__ float xs[RPB][N_];
    __shared__ float wsh[N_ * TOPK_];
    __shared__ int   ish[N_ * TOPK_];
    const int t = threadIdx.x;
    const int row0 = blockIdx.x * RPB;

    for (int i = t; i < N_ * TOPK_; i += 512) { wsh[i] = w[i]; ish[i] = idx[i]; }
    {   // x rows as float4
        const float4* xg = (const float4*)(x + (size_t)row0 * N_);
        float4* xsf = (float4*)&xs[0][0];
        xsf[t] = xg[t];
        xsf[t + 512] = xg[t + 512];
    }
    __syncthreads();

    // score: wave wv handles row wv
    {
        const int wv = t >> 6, lane = t & 63;
        float sa = 0.f;
        #pragma unroll
        for (int i = 0; i < 8; ++i) sa += xs[wv][lane + i * 64] * Wscore[lane + i * 64];
        for (int off = 32; off > 0; off >>= 1) sa += __shfl_down(sa, off);
        if (lane == 0) s[row0 + wv] = sa + bscore[0];
    }

    float wr[TOPK_]; int ir[TOPK_];
    #pragma unroll
    for (int k = 0; k < TOPK_; ++k) { wr[k] = wsh[t * TOPK_ + k]; ir[k] = ish[t * TOPK_ + k]; }
    #pragma unroll
    for (int r = 0; r < RPB; ++r) {
        float acc = 0.f;
        #pragma unroll
        for (int k = 0; k < TOPK_; ++k) acc += wr[k] * xs[r][ir[k]];
        ring[(size_t)(row0 + r) * N_ + t] = __float2bfloat16(acc);
    }
}

// ---------------------------------------------------------------------------
// Kernel 3: softmax over L per batch (in place on s)
// ---------------------------------------------------------------------------
__global__ __launch_bounds__(256) void attn_softmax_kernel(float* __restrict__ s)
{
    const int b = blockIdx.x;
    const int t = threadIdx.x;
    float* row = s + (size_t)b * L_;

    __shared__ float sm[4];
    __shared__ float sm2[4];

    float lmax = -1e30f;
    for (int l = t; l < L_; l += 256) lmax = fmaxf(lmax, row[l]);
    for (int off = 32; off > 0; off >>= 1) lmax = fmaxf(lmax, __shfl_down(lmax, off));
    if ((t & 63) == 0) sm[t >> 6] = lmax;
    __syncthreads();
    float gmax = fmaxf(fmaxf(sm[0], sm[1]), fmaxf(sm[2], sm[3]));

    float lsum = 0.f;
    for (int l = t; l < L_; l += 256) {
        float e = expf(row[l] - gmax);
        row[l] = e;
        lsum += e;
    }
    for (int off = 32; off > 0; off >>= 1) lsum += __shfl_down(lsum, off);
    if ((t & 63) == 0) sm2[t >> 6] = lsum;
    __syncthreads();
    float inv = 1.f / (sm2[0] + sm2[1] + sm2[2] + sm2[3]);
    for (int l = t; l < L_; l += 256) row[l] *= inv;
}

// ---------------------------------------------------------------------------
// Kernel 4: partial center_raw. grid 256 blocks: b = bx>>3, chunk c = bx&7
// covers l in [c*90, c*90+90). craw_p[(b*8+c)*512+n]
// ---------------------------------------------------------------------------
__global__ __launch_bounds__(512) void center_raw_kernel(
    const float* __restrict__ x, const float* __restrict__ attn,
    float* __restrict__ craw_p)
{
    const int b = blockIdx.x >> 3;
    const int c = blockIdx.x & 7;
    const int n = threadIdx.x;
    __shared__ float ash[90];
    const int l0 = c * 90;
    if (n < 90) ash[n] = attn[b * L_ + l0 + n];
    __syncthreads();
    const float* xb = x + ((size_t)b * L_ + l0) * N_;
    float acc = 0.f;
    #pragma unroll 2
    for (int l = 0; l < 90; l++) acc += ash[l] * xb[(size_t)l * N_ + n];
    craw_p[(size_t)(b * 8 + c) * N_ + n] = acc;
}

__device__ __forceinline__ float gelu_exact(float v) {
    return 0.5f * v * (1.0f + erff(v * 0.70710678118654752440f));
}

// ---------------------------------------------------------------------------
// Kernel 5: reduce partials + center MLP + cg[b,n] = center·Wg[512:,n]+bg[n]
// ---------------------------------------------------------------------------
__global__ __launch_bounds__(512) void center_mlp_kernel(
    const float* __restrict__ craw_p,
    const float* __restrict__ Wc1, const float* __restrict__ bc1,
    const float* __restrict__ Wc2, const float* __restrict__ bc2,
    const float* __restrict__ Wcn, const float* __restrict__ bcn,
    const float* __restrict__ Wg,  const float* __restrict__ bg,
    float* __restrict__ center, float* __restrict__ cg)
{
    const int b = blockIdx.x;
    const int t = threadIdx.x;
    __shared__ float cr[N_];
    __shared__ float h1[D_];
    __shared__ float h2[D_];
    __shared__ float cent[N_];

    {
        float acc = 0.f;
        #pragma unroll
        for (int c = 0; c < 8; ++c) acc += craw_p[(size_t)(b * 8 + c) * N_ + t];
        cr[t] = acc;
    }
    __syncthreads();
    if (t < D_) {
        float acc = bc1[t];
        for (int m = 0; m < N_; m++) acc += cr[m] * Wc1[m * D_ + t];
        h1[t] = gelu_exact(acc);
    }
    __syncthreads();
    if (t < D_) {
        float acc = bc2[t];
        #pragma unroll 8
        for (int j = 0; j < D_; j++) acc += h1[j] * Wc2[j * D_ + t];
        h2[t] = gelu_exact(acc);
    }
    __syncthreads();
    {
        float acc = bcn[t];
        #pragma unroll 8
        for (int j = 0; j < D_; j++) acc += h2[j] * Wcn[j * N_ + t];
        center[b * N_ + t] = acc;
        cent[t] = acc;
    }
    __syncthreads();
    {
        float acc = bg[t];
        const float* p = Wg + (size_t)N_ * N_ + t;
        #pragma unroll 4
        for (int m = 0; m < N_; m++) { acc += cent[m] * p[0]; p += N_; }
        cg[b * N_ + t] = acc;
    }
}

// ---------------------------------------------------------------------------
// Kernel 6: transpose+convert Wg-top / Wf to bf16 (N x K row-major)
// ---------------------------------------------------------------------------
__global__ __launch_bounds__(256) void convert_kernel(
    const float* __restrict__ Wg, const float* __restrict__ Wf,
    __hip_bfloat16* __restrict__ WgT, __hip_bfloat16* __restrict__ WfT)
{
    const int n = blockIdx.x & 511;
    const bool isf = blockIdx.x >= 512;
    const float* src = isf ? Wf : Wg;
    __hip_bfloat16* dst = isf ? WfT : WgT;
    for (int k = threadIdx.x; k < N_; k += 256)
        dst[n * N_ + k] = __float2bfloat16(src[(size_t)k * N_ + n]);
}

// ---------------------------------------------------------------------------
// GEMM core (m97 structure): C(128x128) = A(128x512) @ BT(128x512)^T.
// 256 threads = 4 waves; wave (wr,wc) owns 64x64 via 2x2 MFMA 32x32x16.
// BK=64. Staging: global_load_lds dwordx4, XOR-swizzled chunk layout.
// LDS: Ash/Bsh 128 rows x 64 bf16 linear (8 chunks/row, chunk j at pos
// j ^ (row&7)).  16 KB each.
// ---------------------------------------------------------------------------
#define GEMM_BODY(EPILOGUE)                                                    \
    __shared__ __hip_bfloat16 Ash[128 * 64];                                   \
    __shared__ __hip_bfloat16 Bsh[128 * 64];                                   \
    const int tid  = threadIdx.x;                                              \
    const int lane = tid & 63;                                                 \
    const int wv   = tid >> 6;                                                 \
    const int m32  = lane & 31;                                                \
    const int half = lane >> 5;                                                \
    const int wr   = wv >> 1;                                                  \
    const int wc   = wv & 1;                                                   \
    const int row0 = blockIdx.x * 128;                                         \
    const int n0   = blockIdx.y * 128;                                         \
    const int swz  = (lane & 7) ^ (lane >> 3);                                 \
    const int rln  = lane >> 3;                                                \
    f32x16 acc[2][2];                                                          \
    _Pragma("unroll") for (int i = 0; i < 2; i++)                              \
        _Pragma("unroll") for (int j = 0; j < 2; j++)                          \
            _Pragma("unroll") for (int e = 0; e < 16; e++) acc[i][j][e] = 0.f; \
    for (int step = 0; step < 8; ++step) {                                     \
        const int k0 = step * 64;                                              \
        const __hip_bfloat16* Ab = A  + (size_t)row0 * N_ + k0 + swz * 8;      \
        const __hip_bfloat16* Bb = BT + (size_t)n0   * N_ + k0 + swz * 8;      \
        __syncthreads();                                                       \
        _Pragma("unroll") for (int j = 0; j < 4; ++j) {                        \
            const int r = j * 32 + wv * 8 + rln;                               \
            const int lb = (j * 256 + wv * 64) * 8;                            \
            async_cp16(Ab + (size_t)r * N_, Ash + lb);                         \
            async_cp16(Bb + (size_t)r * N_, Bsh + lb);                         \
        }                                                                      \
        __syncthreads();                                                       \
        _Pragma("unroll") for (int ks = 0; ks < 4; ++ks) {                     \
            const int j0 = ks * 2 + half;                                      \
            bf16x8 a0 = frag_ld(Ash, wr * 64      + m32, j0);                  \
            bf16x8 a1 = frag_ld(Ash, wr * 64 + 32 + m32, j0);                  \
            bf16x8 b0 = frag_ld(Bsh, wc * 64      + m32, j0);                  \
            bf16x8 b1 = frag_ld(Bsh, wc * 64 + 32 + m32, j0);                  \
            acc[0][0] = __builtin_amdgcn_mfma_f32_32x32x16_bf16(a0, b0, acc[0][0], 0, 0, 0); \
            acc[0][1] = __builtin_amdgcn_mfma_f32_32x32x16_bf16(a0, b1, acc[0][1], 0, 0, 0); \
            acc[1][0] = __builtin_amdgcn_mfma_f32_32x32x16_bf16(a1, b0, acc[1][0], 0, 0, 0); \
            acc[1][1] = __builtin_amdgcn_mfma_f32_32x32x16_bf16(a1, b1, acc[1][1], 0, 0, 0); \
        }                                                                      \
    }                                                                          \
    _Pragma("unroll") for (int mi = 0; mi < 2; ++mi)                           \
        _Pragma("unroll") for (int ni = 0; ni < 2; ++ni)                       \
            _Pragma("unroll") for (int reg = 0; reg < 16; ++reg) {             \
                const int rg  = row0 + wr * 64 + mi * 32 +                     \
                                (reg & 3) + 8 * (reg >> 2) + 4 * half;         \
                const int col = n0 + wc * 64 + ni * 32 + m32;                  \
                const float aval = acc[mi][ni][reg];                           \
                EPILOGUE                                                       \
            }

// Kernel 7: gate GEMM; fused = sigmoid(ring@WgT^T + cg)*ring + (1-g)*center
__global__ __launch_bounds__(256) void gemm_gate_kernel(
    const __hip_bfloat16* __restrict__ A,    // ring (M,512) bf16
    const __hip_bfloat16* __restrict__ BT,   // WgT (512,512) bf16
    const float* __restrict__ cg,
    const float* __restrict__ center,
    __hip_bfloat16* __restrict__ fused)
{
    GEMM_BODY({
        const int b = rg / L_;
        const float logit = aval + cg[b * N_ + col];
        const float g = 1.f / (1.f + expf(-logit));
        const float rv = __bfloat162float(A[(size_t)rg * N_ + col]);
        const float f = g * rv + (1.f - g) * center[b * N_ + col];
        fused[(size_t)rg * N_ + col] = __float2bfloat16(f);
    })
}

// Kernel 8: output GEMM; h = fused@WfT^T + bf + x  (fp32 -> d_out)
__global__ __launch_bounds__(256) void gemm_out_kernel(
    const __hip_bfloat16* __restrict__ A,    // fused (M,512) bf16
    const __hip_bfloat16* __restrict__ BT,   // WfT (512,512) bf16
    const float* __restrict__ x,
    const float* __restrict__ bfv,
    float* __restrict__ out)
{
    GEMM_BODY({
        out[(size_t)rg * N_ + col] = aval + bfv[col] + x[(size_t)rg * N_ + col];
    })
}

// ---------------------------------------------------------------------------
// Kernel 9: LayerNorm, 4 rows/block, float4. 512 threads: row r = tid>>7,
// 128 threads per row (2 waves/row).
// ---------------------------------------------------------------------------
__global__ __launch_bounds__(512) void ln_kernel(
    float* __restrict__ out,
    const float* __restrict__ gamma, const float* __restrict__ beta)
{
    const int tid = threadIdx.x;
    const int r = tid >> 7;               // 0..3
    const int c = tid & 127;              // float4 index within row
    const int row = blockIdx.x * 4 + r;
    const int wid = tid >> 6;             // 0..7
    __shared__ float ls[8], lq[8];

    float4 v = ((const float4*)(out + (size_t)row * N_))[c];
    float sum = v.x + v.y + v.z + v.w;
    float sq  = v.x * v.x + v.y * v.y + v.z * v.z + v.w * v.w;
    for (int off = 32; off > 0; off >>= 1) {
        sum += __shfl_down(sum, off);
        sq  += __shfl_down(sq,  off);
    }
    if ((tid & 63) == 0) { ls[wid] = sum; lq[wid] = sq; }
    __syncthreads();
    const float S  = ls[2 * r] + ls[2 * r + 1];
    const float Q2 = lq[2 * r] + lq[2 * r + 1];
    const float mu  = S * (1.0f / N_);
    const float var = Q2 * (1.0f / N_) - mu * mu;
    const float inv = 1.0f / sqrtf(var + 1e-5f);
    const float4 g4 = ((const float4*)gamma)[c];
    const float4 b4 = ((const float4*)beta)[c];
    float4 o;
    o.x = (v.x - mu) * inv * g4.x + b4.x;
    o.y = (v.y - mu) * inv * g4.y + b4.y;
    o.z = (v.z - mu) * inv * g4.z + b4.z;
    o.w = (v.w - mu) * inv * g4.w + b4.w;
    ((float4*)(out + (size_t)row * N_))[c] = o;
}

// ---------------------------------------------------------------------------
extern "C" void kernel_launch(void* const* d_in, const int* in_sizes, int n_in,
                              void* d_out, int out_size, void* d_ws, size_t ws_size,
                              hipStream_t stream) {
    const float* x       = (const float*)d_in[0];
    const float* ve      = (const float*)d_in[1];
    const float* Wq      = (const float*)d_in[2];
    const float* bq      = (const float*)d_in[3];
    const float* Wk      = (const float*)d_in[4];
    const float* bk      = (const float*)d_in[5];
    const float* Wscore  = (const float*)d_in[6];
    const float* bscore  = (const float*)d_in[7];
    const float* Wc1     = (const float*)d_in[8];
    const float* bc1     = (const float*)d_in[9];
    const float* Wc2     = (const float*)d_in[10];
    const float* bc2     = (const float*)d_in[11];
    const float* Wcn     = (const float*)d_in[12];
    const float* bcn     = (const float*)d_in[13];
    const float* Wg      = (const float*)d_in[14];
    const float* bg      = (const float*)d_in[15];
    const float* Wf      = (const float*)d_in[16];
    const float* bf      = (const float*)d_in[17];
    const float* gamma   = (const float*)d_in[18];
    const float* beta    = (const float*)d_in[19];
    float* out = (float*)d_out;

    char* p = (char*)d_ws;
    float* ws_w    = (float*)p; p += N_ * TOPK_ * sizeof(float);
    int*   ws_idx  = (int*)p;   p += N_ * TOPK_ * sizeof(int);
    float* ws_s    = (float*)p; p += B_ * L_ * sizeof(float);
    float* ws_crp  = (float*)p; p += B_ * 8 * N_ * sizeof(float);
    float* ws_cent = (float*)p; p += B_ * N_ * sizeof(float);
    float* ws_cg   = (float*)p; p += B_ * N_ * sizeof(float);
    __hip_bfloat16* ws_ring  = (__hip_bfloat16*)p; p += (size_t)M_ * N_ * sizeof(__hip_bfloat16);
    __hip_bfloat16* ws_fused = (__hip_bfloat16*)p; p += (size_t)M_ * N_ * sizeof(__hip_bfloat16);
    __hip_bfloat16* ws_WgT   = (__hip_bfloat16*)p; p += (size_t)N_ * N_ * sizeof(__hip_bfloat16);
    __hip_bfloat16* ws_WfT   = (__hip_bfloat16*)p; p += (size_t)N_ * N_ * sizeof(__hip_bfloat16);

    convert_kernel<<<1024, 256, 0, stream>>>(Wg, Wf, ws_WgT, ws_WfT);
    topk_kernel<<<N_, 512, 0, stream>>>(ve, Wq, bq, Wk, bk, ws_w, ws_idx);
    ring_kernel<<<M_ / RPB, 512, 0, stream>>>(x, ws_w, ws_idx, Wscore, bscore,
                                              ws_ring, ws_s);
    attn_softmax_kernel<<<B_, 256, 0, stream>>>(ws_s);
    center_raw_kernel<<<B_ * 8, 512, 0, stream>>>(x, ws_s, ws_crp);
    center_mlp_kernel<<<B_, 512, 0, stream>>>(ws_crp, Wc1, bc1, Wc2, bc2,
                                              Wcn, bcn, Wg, bg, ws_cent, ws_cg);
    dim3 ggrid(M_ / 128, N_ / 128);
    gemm_gate_kernel<<<ggrid, 256, 0, stream>>>(ws_ring, ws_WgT, ws_cg,
                                                ws_cent, ws_fused);
    gemm_out_kernel<<<ggrid, 256, 0, stream>>>(ws_fused, ws_WfT, x, bf, out);
    ln_kernel<<<M_ / 4, 512, 0, stream>>>(out, gamma, beta);
}

// Round 4
// 296.712 us; speedup vs baseline: 5.8566x; 1.1420x over previous
//
#include <hip/hip_runtime.h>
#include <hip/hip_bf16.h>
#include <math.h>

#define B_ 32
#define L_ 720
#define N_ 512
#define H_ 16
#define D_ 64
#define TOPK_ 8
#define M_ (B_ * L_)          // 23040 rows
#define RPB 8                 // rows per ring block
#define CRCH 16               // center_raw chunks per batch
#define CRL (L_ / CRCH)       // 45

typedef __bf16 bf16x8 __attribute__((ext_vector_type(8)));
typedef float f32x16 __attribute__((ext_vector_type(16)));

// ---------------------------------------------------------------------------
// async 16B global -> LDS (dest = wave-uniform lds base + lane*16)
// ---------------------------------------------------------------------------
__device__ __forceinline__ void async_cp16(const __hip_bfloat16* g, __hip_bfloat16* l) {
    __builtin_amdgcn_global_load_lds(
        (const __attribute__((address_space(1))) void*)g,
        (__attribute__((address_space(3))) void*)l, 16, 0, 0);
}

__device__ __forceinline__ bf16x8 frag_ld(const __hip_bfloat16* base, int row, int j0) {
    return *(const bf16x8*)(base + row * 64 + (((j0) ^ (row & 7)) << 3));
}

// ---------------------------------------------------------------------------
// Kernel 1: top-8 neighbors. One wave per row n; shuffle-only selection.
// ---------------------------------------------------------------------------
__global__ __launch_bounds__(64) void topk_kernel(
    const float* __restrict__ ve,
    const float* __restrict__ Wq, const float* __restrict__ bq,
    const float* __restrict__ Wk, const float* __restrict__ bk,
    float* __restrict__ w_out, int* __restrict__ idx_out)
{
    const int n = blockIdx.x;
    const int lane = threadIdx.x;

    // Q[n][h] computed redundantly on every lane (16x16 = 256 MACs)
    float Q[H_];
    {
        float vn[H_];
        #pragma unroll
        for (int j = 0; j < H_; j++) vn[j] = ve[n * H_ + j];
        #pragma unroll
        for (int h = 0; h < H_; h++) {
            float q = bq[h];
            #pragma unroll
            for (int j = 0; j < H_; j++) q += vn[j] * Wq[j * H_ + h];
            Q[h] = q;
        }
    }

    // 8 candidate columns per lane: j = c*64 + lane
    float sv[8]; int si[8];
    #pragma unroll
    for (int c = 0; c < 8; ++c) {
        const int j = c * 64 + lane;
        float vr[H_];
        #pragma unroll
        for (int jj = 0; jj < H_; jj++) vr[jj] = ve[j * H_ + jj];
        float s = 0.f;
        #pragma unroll
        for (int h = 0; h < H_; h++) {
            float kk = bk[h];
            #pragma unroll
            for (int jj = 0; jj < H_; jj++) kk += vr[jj] * Wk[jj * H_ + h];
            s += Q[h] * kk;
        }
        sv[c] = (j == n) ? -1e9f : s;
        si[c] = j;
    }

    // iterative top-8 via wave argmax (tie -> lowest index)
    float keepv[TOPK_]; int keepi[TOPK_];
    #pragma unroll
    for (int k = 0; k < TOPK_; ++k) {
        float bv = sv[0]; int bi = si[0]; int bslot = 0;
        #pragma unroll
        for (int c = 1; c < 8; ++c)
            if (sv[c] > bv || (sv[c] == bv && si[c] < bi)) { bv = sv[c]; bi = si[c]; bslot = c; }
        float v = bv; int i = bi;
        #pragma unroll
        for (int off = 32; off > 0; off >>= 1) {
            float v2 = __shfl_xor(v, off);
            int   i2 = __shfl_xor(i, off);
            if (v2 > v || (v2 == v && i2 < i)) { v = v2; i = i2; }
        }
        keepv[k] = v; keepi[k] = i;
        if (i == bi) sv[bslot] = -INFINITY;   // unique indices -> only owner fires
    }

    if (lane == 0) {
        float vmax = keepv[0];
        float ev[TOPK_], esum = 0.f;
        #pragma unroll
        for (int k = 0; k < TOPK_; k++) { ev[k] = expf(keepv[k] - vmax); esum += ev[k]; }
        float inv = 1.f / esum;
        #pragma unroll
        for (int k = 0; k < TOPK_; k++) {
            w_out[n * TOPK_ + k] = ev[k] * inv;
            idx_out[n * TOPK_ + k] = keepi[k];
        }
    }
}

// ---------------------------------------------------------------------------
// Kernel 2: ring gather -> bf16 A matrix, fused with score s = x·Wscore+b.
// ---------------------------------------------------------------------------
__global__ __launch_bounds__(512) void ring_kernel(
    const float* __restrict__ x, const float* __restrict__ w,
    const int* __restrict__ idx,
    const float* __restrict__ Wscore, const float* __restrict__ bscore,
    __hip_bfloat16* __restrict__ ring, float* __restrict__ s)
{
    __shared__ float xs[RPB][N_];
    __shared__ float wsh[N_ * TOPK_];
    __shared__ int   ish[N_ * TOPK_];
    const int t = threadIdx.x;
    const int row0 = blockIdx.x * RPB;

    for (int i = t; i < N_ * TOPK_; i += 512) { wsh[i] = w[i]; ish[i] = idx[i]; }
    {
        const float4* xg = (const float4*)(x + (size_t)row0 * N_);
        float4* xsf = (float4*)&xs[0][0];
        xsf[t] = xg[t];
        xsf[t + 512] = xg[t + 512];
    }
    __syncthreads();

    {
        const int wv = t >> 6, lane = t & 63;
        float sa = 0.f;
        #pragma unroll
        for (int i = 0; i < 8; ++i) sa += xs[wv][lane + i * 64] * Wscore[lane + i * 64];
        for (int off = 32; off > 0; off >>= 1) sa += __shfl_down(sa, off);
        if (lane == 0) s[row0 + wv] = sa + bscore[0];
    }

    float wr[TOPK_]; int ir[TOPK_];
    #pragma unroll
    for (int k = 0; k < TOPK_; ++k) { wr[k] = wsh[t * TOPK_ + k]; ir[k] = ish[t * TOPK_ + k]; }
    #pragma unroll
    for (int r = 0; r < RPB; ++r) {
        float acc = 0.f;
        #pragma unroll
        for (int k = 0; k < TOPK_; ++k) acc += wr[k] * xs[r][ir[k]];
        ring[(size_t)(row0 + r) * N_ + t] = __float2bfloat16(acc);
    }
}

// ---------------------------------------------------------------------------
// Kernel 3: softmax over L per batch (in place on s)
// ---------------------------------------------------------------------------
__global__ __launch_bounds__(256) void attn_softmax_kernel(float* __restrict__ s)
{
    const int b = blockIdx.x;
    const int t = threadIdx.x;
    float* row = s + (size_t)b * L_;

    __shared__ float sm[4];
    __shared__ float sm2[4];

    float lmax = -1e30f;
    for (int l = t; l < L_; l += 256) lmax = fmaxf(lmax, row[l]);
    for (int off = 32; off > 0; off >>= 1) lmax = fmaxf(lmax, __shfl_down(lmax, off));
    if ((t & 63) == 0) sm[t >> 6] = lmax;
    __syncthreads();
    float gmax = fmaxf(fmaxf(sm[0], sm[1]), fmaxf(sm[2], sm[3]));

    float lsum = 0.f;
    for (int l = t; l < L_; l += 256) {
        float e = expf(row[l] - gmax);
        row[l] = e;
        lsum += e;
    }
    for (int off = 32; off > 0; off >>= 1) lsum += __shfl_down(lsum, off);
    if ((t & 63) == 0) sm2[t >> 6] = lsum;
    __syncthreads();
    float inv = 1.f / (sm2[0] + sm2[1] + sm2[2] + sm2[3]);
    for (int l = t; l < L_; l += 256) row[l] *= inv;
}

// ---------------------------------------------------------------------------
// Kernel 4: partial center_raw. grid B_*CRCH: b = bx>>4, chunk c = bx&15.
// ---------------------------------------------------------------------------
__global__ __launch_bounds__(512) void center_raw_kernel(
    const float* __restrict__ x, const float* __restrict__ attn,
    float* __restrict__ craw_p)
{
    const int b = blockIdx.x >> 4;
    const int c = blockIdx.x & 15;
    const int n = threadIdx.x;
    __shared__ float ash[CRL];
    const int l0 = c * CRL;
    if (n < CRL) ash[n] = attn[b * L_ + l0 + n];
    __syncthreads();
    const float* xb = x + ((size_t)b * L_ + l0) * N_;
    float acc = 0.f;
    #pragma unroll 3
    for (int l = 0; l < CRL; l++) acc += ash[l] * xb[(size_t)l * N_ + n];
    craw_p[(size_t)(b * CRCH + c) * N_ + n] = acc;
}

__device__ __forceinline__ float gelu_exact(float v) {
    return 0.5f * v * (1.0f + erff(v * 0.70710678118654752440f));
}

// ---------------------------------------------------------------------------
// Kernel 5: reduce partials + center MLP -> center. grid B_, 512 thr.
// First matmul (512->64) split 8 ways across threads.
// ---------------------------------------------------------------------------
__global__ __launch_bounds__(512) void center_mlp_kernel(
    const float* __restrict__ craw_p,
    const float* __restrict__ Wc1, const float* __restrict__ bc1,
    const float* __restrict__ Wc2, const float* __restrict__ bc2,
    const float* __restrict__ Wcn, const float* __restrict__ bcn,
    float* __restrict__ center)
{
    const int b = blockIdx.x;
    const int t = threadIdx.x;
    const int col = t & 63;
    const int seg = t >> 6;
    __shared__ float cr[N_];
    __shared__ float psum[8][D_];
    __shared__ float h1[D_];
    __shared__ float h2[D_];

    {
        float acc = 0.f;
        #pragma unroll
        for (int c = 0; c < CRCH; ++c) acc += craw_p[(size_t)(b * CRCH + c) * N_ + t];
        cr[t] = acc;
    }
    __syncthreads();
    {   // h1 partials: thread (seg,col) covers m in [seg*64, seg*64+64)
        float p = 0.f;
        #pragma unroll 8
        for (int m = seg * 64; m < seg * 64 + 64; ++m) p += cr[m] * Wc1[m * D_ + col];
        psum[seg][col] = p;
    }
    __syncthreads();
    if (t < D_) {
        float acc = bc1[t];
        #pragma unroll
        for (int s2 = 0; s2 < 8; ++s2) acc += psum[s2][t];
        h1[t] = gelu_exact(acc);
    }
    __syncthreads();
    if (t < D_) {
        float acc = bc2[t];
        #pragma unroll 8
        for (int j = 0; j < D_; j++) acc += h1[j] * Wc2[j * D_ + t];
        h2[t] = gelu_exact(acc);
    }
    __syncthreads();
    {
        float acc = bcn[t];
        #pragma unroll 8
        for (int j = 0; j < D_; j++) acc += h2[j] * Wcn[j * N_ + t];
        center[b * N_ + t] = acc;
    }
}

// ---------------------------------------------------------------------------
// Kernel 6: cg[b,n] = center[b]·Wg[512+.,n] + bg[n].
// grid (8 n-chunks, B_), 512 threads, 8-way K-split + LDS reduce.
// ---------------------------------------------------------------------------
__global__ __launch_bounds__(512) void cg_kernel(
    const float* __restrict__ center, const float* __restrict__ Wg,
    const float* __restrict__ bg, float* __restrict__ cg)
{
    const int nc = blockIdx.x;        // 0..7
    const int b  = blockIdx.y;
    const int t  = threadIdx.x;
    const int col = nc * 64 + (t & 63);
    const int seg = t >> 6;
    __shared__ float cs[N_];
    __shared__ float psum[8][64];

    cs[t] = center[b * N_ + t];
    __syncthreads();
    {
        float p = 0.f;
        const float* wp = Wg + (size_t)(N_ + seg * 64) * N_ + col;
        #pragma unroll 8
        for (int m = 0; m < 64; ++m) { p += cs[seg * 64 + m] * wp[0]; wp += N_; }
        psum[seg][t & 63] = p;
    }
    __syncthreads();
    if (t < 64) {
        float acc = bg[nc * 64 + t];
        #pragma unroll
        for (int s2 = 0; s2 < 8; ++s2) acc += psum[s2][t];
        cg[b * N_ + nc * 64 + t] = acc;
    }
}

// ---------------------------------------------------------------------------
// Kernel 7: transpose+convert Wg-top / Wf to bf16 (N x K row-major)
// ---------------------------------------------------------------------------
__global__ __launch_bounds__(256) void convert_kernel(
    const float* __restrict__ Wg, const float* __restrict__ Wf,
    __hip_bfloat16* __restrict__ WgT, __hip_bfloat16* __restrict__ WfT)
{
    const int n = blockIdx.x & 511;
    const bool isf = blockIdx.x >= 512;
    const float* src = isf ? Wf : Wg;
    __hip_bfloat16* dst = isf ? WfT : WgT;
    for (int k = threadIdx.x; k < N_; k += 256)
        dst[n * N_ + k] = __float2bfloat16(src[(size_t)k * N_ + n]);
}

// ---------------------------------------------------------------------------
// GEMM core (m97 structure): C(128x128) = A(128x512) @ BT(128x512)^T.
// ---------------------------------------------------------------------------
#define GEMM_BODY(EPILOGUE)                                                    \
    __shared__ __hip_bfloat16 Ash[128 * 64];                                   \
    __shared__ __hip_bfloat16 Bsh[128 * 64];                                   \
    const int tid  = threadIdx.x;                                              \
    const int lane = tid & 63;                                                 \
    const int wv   = tid >> 6;                                                 \
    const int m32  = lane & 31;                                                \
    const int half = lane >> 5;                                                \
    const int wr   = wv >> 1;                                                  \
    const int wc   = wv & 1;                                                   \
    const int row0 = blockIdx.x * 128;                                         \
    const int n0   = blockIdx.y * 128;                                         \
    const int swz  = (lane & 7) ^ (lane >> 3);                                 \
    const int rln  = lane >> 3;                                                \
    f32x16 acc[2][2];                                                          \
    _Pragma("unroll") for (int i = 0; i < 2; i++)                              \
        _Pragma("unroll") for (int j = 0; j < 2; j++)                          \
            _Pragma("unroll") for (int e = 0; e < 16; e++) acc[i][j][e] = 0.f; \
    for (int step = 0; step < 8; ++step) {                                     \
        const int k0 = step * 64;                                              \
        const __hip_bfloat16* Ab = A  + (size_t)row0 * N_ + k0 + swz * 8;      \
        const __hip_bfloat16* Bb = BT + (size_t)n0   * N_ + k0 + swz * 8;      \
        __syncthreads();                                                       \
        _Pragma("unroll") for (int j = 0; j < 4; ++j) {                        \
            const int r = j * 32 + wv * 8 + rln;                               \
            const int lb = (j * 256 + wv * 64) * 8;                            \
            async_cp16(Ab + (size_t)r * N_, Ash + lb);                         \
            async_cp16(Bb + (size_t)r * N_, Bsh + lb);                         \
        }                                                                      \
        __syncthreads();                                                       \
        _Pragma("unroll") for (int ks = 0; ks < 4; ++ks) {                     \
            const int j0 = ks * 2 + half;                                      \
            bf16x8 a0 = frag_ld(Ash, wr * 64      + m32, j0);                  \
            bf16x8 a1 = frag_ld(Ash, wr * 64 + 32 + m32, j0);                  \
            bf16x8 b0 = frag_ld(Bsh, wc * 64      + m32, j0);                  \
            bf16x8 b1 = frag_ld(Bsh, wc * 64 + 32 + m32, j0);                  \
            acc[0][0] = __builtin_amdgcn_mfma_f32_32x32x16_bf16(a0, b0, acc[0][0], 0, 0, 0); \
            acc[0][1] = __builtin_amdgcn_mfma_f32_32x32x16_bf16(a0, b1, acc[0][1], 0, 0, 0); \
            acc[1][0] = __builtin_amdgcn_mfma_f32_32x32x16_bf16(a1, b0, acc[1][0], 0, 0, 0); \
            acc[1][1] = __builtin_amdgcn_mfma_f32_32x32x16_bf16(a1, b1, acc[1][1], 0, 0, 0); \
        }                                                                      \
    }                                                                          \
    _Pragma("unroll") for (int mi = 0; mi < 2; ++mi)                           \
        _Pragma("unroll") for (int ni = 0; ni < 2; ++ni)                       \
            _Pragma("unroll") for (int reg = 0; reg < 16; ++reg) {             \
                const int rg  = row0 + wr * 64 + mi * 32 +                     \
                                (reg & 3) + 8 * (reg >> 2) + 4 * half;         \
                const int col = n0 + wc * 64 + ni * 32 + m32;                  \
                const float aval = acc[mi][ni][reg];                           \
                EPILOGUE                                                       \
            }

// Kernel 8: gate GEMM; fused = sigmoid(ring@WgT^T + cg)*ring + (1-g)*center
__global__ __launch_bounds__(256) void gemm_gate_kernel(
    const __hip_bfloat16* __restrict__ A,
    const __hip_bfloat16* __restrict__ BT,
    const float* __restrict__ cg,
    const float* __restrict__ center,
    __hip_bfloat16* __restrict__ fused)
{
    GEMM_BODY({
        const int b = rg / L_;
        const float logit = aval + cg[b * N_ + col];
        const float g = 1.f / (1.f + expf(-logit));
        const float rv = __bfloat162float(A[(size_t)rg * N_ + col]);
        const float f = g * rv + (1.f - g) * center[b * N_ + col];
        fused[(size_t)rg * N_ + col] = __float2bfloat16(f);
    })
}

// Kernel 9: output GEMM; h = fused@WfT^T + bf + x  (fp32 -> d_out)
__global__ __launch_bounds__(256) void gemm_out_kernel(
    const __hip_bfloat16* __restrict__ A,
    const __hip_bfloat16* __restrict__ BT,
    const float* __restrict__ x,
    const float* __restrict__ bfv,
    float* __restrict__ out)
{
    GEMM_BODY({
        out[(size_t)rg * N_ + col] = aval + bfv[col] + x[(size_t)rg * N_ + col];
    })
}

// ---------------------------------------------------------------------------
// Kernel 10: LayerNorm, 4 rows/block, float4.
// ---------------------------------------------------------------------------
__global__ __launch_bounds__(512) void ln_kernel(
    float* __restrict__ out,
    const float* __restrict__ gamma, const float* __restrict__ beta)
{
    const int tid = threadIdx.x;
    const int r = tid >> 7;
    const int c = tid & 127;
    const int row = blockIdx.x * 4 + r;
    const int wid = tid >> 6;
    __shared__ float ls[8], lq[8];

    float4 v = ((const float4*)(out + (size_t)row * N_))[c];
    float sum = v.x + v.y + v.z + v.w;
    float sq  = v.x * v.x + v.y * v.y + v.z * v.z + v.w * v.w;
    for (int off = 32; off > 0; off >>= 1) {
        sum += __shfl_down(sum, off);
        sq  += __shfl_down(sq,  off);
    }
    if ((tid & 63) == 0) { ls[wid] = sum; lq[wid] = sq; }
    __syncthreads();
    const float S  = ls[2 * r] + ls[2 * r + 1];
    const float Q2 = lq[2 * r] + lq[2 * r + 1];
    const float mu  = S * (1.0f / N_);
    const float var = Q2 * (1.0f / N_) - mu * mu;
    const float inv = 1.0f / sqrtf(var + 1e-5f);
    const float4 g4 = ((const float4*)gamma)[c];
    const float4 b4 = ((const float4*)beta)[c];
    float4 o;
    o.x = (v.x - mu) * inv * g4.x + b4.x;
    o.y = (v.y - mu) * inv * g4.y + b4.y;
    o.z = (v.z - mu) * inv * g4.z + b4.z;
    o.w = (v.w - mu) * inv * g4.w + b4.w;
    ((float4*)(out + (size_t)row * N_))[c] = o;
}

// ---------------------------------------------------------------------------
extern "C" void kernel_launch(void* const* d_in, const int* in_sizes, int n_in,
                              void* d_out, int out_size, void* d_ws, size_t ws_size,
                              hipStream_t stream) {
    const float* x       = (const float*)d_in[0];
    const float* ve      = (const float*)d_in[1];
    const float* Wq      = (const float*)d_in[2];
    const float* bq      = (const float*)d_in[3];
    const float* Wk      = (const float*)d_in[4];
    const float* bk      = (const float*)d_in[5];
    const float* Wscore  = (const float*)d_in[6];
    const float* bscore  = (const float*)d_in[7];
    const float* Wc1     = (const float*)d_in[8];
    const float* bc1     = (const float*)d_in[9];
    const float* Wc2     = (const float*)d_in[10];
    const float* bc2     = (const float*)d_in[11];
    const float* Wcn     = (const float*)d_in[12];
    const float* bcn     = (const float*)d_in[13];
    const float* Wg      = (const float*)d_in[14];
    const float* bg      = (const float*)d_in[15];
    const float* Wf      = (const float*)d_in[16];
    const float* bf      = (const float*)d_in[17];
    const float* gamma   = (const float*)d_in[18];
    const float* beta    = (const float*)d_in[19];
    float* out = (float*)d_out;

    char* p = (char*)d_ws;
    float* ws_w    = (float*)p; p += N_ * TOPK_ * sizeof(float);
    int*   ws_idx  = (int*)p;   p += N_ * TOPK_ * sizeof(int);
    float* ws_s    = (float*)p; p += B_ * L_ * sizeof(float);
    float* ws_crp  = (float*)p; p += B_ * CRCH * N_ * sizeof(float);
    float* ws_cent = (float*)p; p += B_ * N_ * sizeof(float);
    float* ws_cg   = (float*)p; p += B_ * N_ * sizeof(float);
    __hip_bfloat16* ws_ring  = (__hip_bfloat16*)p; p += (size_t)M_ * N_ * sizeof(__hip_bfloat16);
    __hip_bfloat16* ws_fused = (__hip_bfloat16*)p; p += (size_t)M_ * N_ * sizeof(__hip_bfloat16);
    __hip_bfloat16* ws_WgT   = (__hip_bfloat16*)p; p += (size_t)N_ * N_ * sizeof(__hip_bfloat16);
    __hip_bfloat16* ws_WfT   = (__hip_bfloat16*)p; p += (size_t)N_ * N_ * sizeof(__hip_bfloat16);

    convert_kernel<<<1024, 256, 0, stream>>>(Wg, Wf, ws_WgT, ws_WfT);
    topk_kernel<<<N_, 64, 0, stream>>>(ve, Wq, bq, Wk, bk, ws_w, ws_idx);
    ring_kernel<<<M_ / RPB, 512, 0, stream>>>(x, ws_w, ws_idx, Wscore, bscore,
                                              ws_ring, ws_s);
    attn_softmax_kernel<<<B_, 256, 0, stream>>>(ws_s);
    center_raw_kernel<<<B_ * CRCH, 512, 0, stream>>>(x, ws_s, ws_crp);
    center_mlp_kernel<<<B_, 512, 0, stream>>>(ws_crp, Wc1, bc1, Wc2, bc2,
                                              Wcn, bcn, ws_cent);
    cg_kernel<<<dim3(8, B_), 512, 0, stream>>>(ws_cent, Wg, bg, ws_cg);
    dim3 ggrid(M_ / 128, N_ / 128);
    gemm_gate_kernel<<<ggrid, 256, 0, stream>>>(ws_ring, ws_WgT, ws_cg,
                                                ws_cent, ws_fused);
    gemm_out_kernel<<<ggrid, 256, 0, stream>>>(ws_fused, ws_WfT, x, bf, out);
    ln_kernel<<<M_ / 4, 512, 0, stream>>>(out, gamma, beta);
}

// Round 5
// 268.751 us; speedup vs baseline: 6.4660x; 1.1040x over previous
//
#include <hip/hip_runtime.h>
#include <hip/hip_bf16.h>
#include <math.h>

#define B_ 32
#define L_ 720
#define N_ 512
#define H_ 16
#define D_ 64
#define TOPK_ 8
#define M_ (B_ * L_)          // 23040 rows
#define RPB 8                 // rows per ring block
#define CRCH 16               // center_raw chunks per batch
#define CRL (L_ / CRCH)       // 45

typedef __bf16 bf16x8 __attribute__((ext_vector_type(8)));
typedef float f32x16 __attribute__((ext_vector_type(16)));

// ---------------------------------------------------------------------------
// async 16B global -> LDS (dest = wave-uniform lds base + lane*16)
// ---------------------------------------------------------------------------
__device__ __forceinline__ void async_cp16(const __hip_bfloat16* g, __hip_bfloat16* l) {
    __builtin_amdgcn_global_load_lds(
        (const __attribute__((address_space(1))) void*)g,
        (__attribute__((address_space(3))) void*)l, 16, 0, 0);
}

__device__ __forceinline__ bf16x8 frag_ld(const __hip_bfloat16* base, int row, int j0) {
    return *(const bf16x8*)(base + row * 64 + (((j0) ^ (row & 7)) << 3));
}

// ---------------------------------------------------------------------------
// Kernel 0: Q = ve@Wq+bq, K = ve@Wk+bk  (512x16 each). grid 16 x 512 thr.
// Thread g covers entry (j = g>>4, h = g&15) of both Q and K.
// ---------------------------------------------------------------------------
__global__ __launch_bounds__(512) void qk_kernel(
    const float* __restrict__ ve,
    const float* __restrict__ Wq, const float* __restrict__ bq,
    const float* __restrict__ Wk, const float* __restrict__ bk,
    float* __restrict__ Qm, float* __restrict__ Km)
{
    const int g = blockIdx.x * 512 + threadIdx.x;   // 0..8191
    const int j = g >> 4, h = g & 15;
    const float* vr = ve + j * H_;
    float q = bq[h], k = bk[h];
    #pragma unroll
    for (int m = 0; m < H_; ++m) {
        const float v = vr[m];
        q += v * Wq[m * H_ + h];
        k += v * Wk[m * H_ + h];
    }
    Qm[g] = q;
    Km[g] = k;
}

// ---------------------------------------------------------------------------
// Kernel 1: top-8 neighbors. One wave per row n; shuffle-only selection.
// Q/K precomputed (32 KB tables -> L1/L2 resident).
// ---------------------------------------------------------------------------
__global__ __launch_bounds__(64) void topk_kernel(
    const float* __restrict__ Qm, const float* __restrict__ Km,
    float* __restrict__ w_out, int* __restrict__ idx_out)
{
    const int n = blockIdx.x;
    const int lane = threadIdx.x;

    // Q row (broadcast load)
    float4 q0, q1, q2, q3;
    {
        const float4* qr = (const float4*)(Qm + n * H_);
        q0 = qr[0]; q1 = qr[1]; q2 = qr[2]; q3 = qr[3];
    }

    // 8 candidate columns per lane: j = c*64 + lane
    float sv[8]; int si[8];
    #pragma unroll
    for (int c = 0; c < 8; ++c) {
        const int j = c * 64 + lane;
        const float4* kr = (const float4*)(Km + j * H_);
        float4 k0 = kr[0], k1 = kr[1], k2 = kr[2], k3 = kr[3];
        float s = q0.x * k0.x + q0.y * k0.y + q0.z * k0.z + q0.w * k0.w
                + q1.x * k1.x + q1.y * k1.y + q1.z * k1.z + q1.w * k1.w
                + q2.x * k2.x + q2.y * k2.y + q2.z * k2.z + q2.w * k2.w
                + q3.x * k3.x + q3.y * k3.y + q3.z * k3.z + q3.w * k3.w;
        sv[c] = (j == n) ? -1e9f : s;
        si[c] = j;
    }

    // iterative top-8 via wave argmax (tie -> lowest index, = jax.lax.top_k)
    float keepv[TOPK_]; int keepi[TOPK_];
    #pragma unroll
    for (int k = 0; k < TOPK_; ++k) {
        float bv = sv[0]; int bi = si[0]; int bslot = 0;
        #pragma unroll
        for (int c = 1; c < 8; ++c)
            if (sv[c] > bv || (sv[c] == bv && si[c] < bi)) { bv = sv[c]; bi = si[c]; bslot = c; }
        float v = bv; int i = bi;
        #pragma unroll
        for (int off = 32; off > 0; off >>= 1) {
            float v2 = __shfl_xor(v, off);
            int   i2 = __shfl_xor(i, off);
            if (v2 > v || (v2 == v && i2 < i)) { v = v2; i = i2; }
        }
        keepv[k] = v; keepi[k] = i;
        if (i == bi) sv[bslot] = -INFINITY;   // unique indices -> only owner fires
    }

    if (lane == 0) {
        float vmax = keepv[0];
        float ev[TOPK_], esum = 0.f;
        #pragma unroll
        for (int k = 0; k < TOPK_; k++) { ev[k] = expf(keepv[k] - vmax); esum += ev[k]; }
        float inv = 1.f / esum;
        #pragma unroll
        for (int k = 0; k < TOPK_; k++) {
            w_out[n * TOPK_ + k] = ev[k] * inv;
            idx_out[n * TOPK_ + k] = keepi[k];
        }
    }
}

// ---------------------------------------------------------------------------
// Kernel 2: ring gather -> bf16 A matrix, fused with score s = x·Wscore+b.
// ---------------------------------------------------------------------------
__global__ __launch_bounds__(512) void ring_kernel(
    const float* __restrict__ x, const float* __restrict__ w,
    const int* __restrict__ idx,
    const float* __restrict__ Wscore, const float* __restrict__ bscore,
    __hip_bfloat16* __restrict__ ring, float* __restrict__ s)
{
    __shared__ float xs[RPB][N_];
    __shared__ float wsh[N_ * TOPK_];
    __shared__ int   ish[N_ * TOPK_];
    const int t = threadIdx.x;
    const int row0 = blockIdx.x * RPB;

    for (int i = t; i < N_ * TOPK_; i += 512) { wsh[i] = w[i]; ish[i] = idx[i]; }
    {
        const float4* xg = (const float4*)(x + (size_t)row0 * N_);
        float4* xsf = (float4*)&xs[0][0];
        xsf[t] = xg[t];
        xsf[t + 512] = xg[t + 512];
    }
    __syncthreads();

    {
        const int wv = t >> 6, lane = t & 63;
        float sa = 0.f;
        #pragma unroll
        for (int i = 0; i < 8; ++i) sa += xs[wv][lane + i * 64] * Wscore[lane + i * 64];
        for (int off = 32; off > 0; off >>= 1) sa += __shfl_down(sa, off);
        if (lane == 0) s[row0 + wv] = sa + bscore[0];
    }

    float wr[TOPK_]; int ir[TOPK_];
    #pragma unroll
    for (int k = 0; k < TOPK_; ++k) { wr[k] = wsh[t * TOPK_ + k]; ir[k] = ish[t * TOPK_ + k]; }
    #pragma unroll
    for (int r = 0; r < RPB; ++r) {
        float acc = 0.f;
        #pragma unroll
        for (int k = 0; k < TOPK_; ++k) acc += wr[k] * xs[r][ir[k]];
        ring[(size_t)(row0 + r) * N_ + t] = __float2bfloat16(acc);
    }
}

// ---------------------------------------------------------------------------
// Kernel 3: softmax over L per batch (in place on s)
// ---------------------------------------------------------------------------
__global__ __launch_bounds__(256) void attn_softmax_kernel(float* __restrict__ s)
{
    const int b = blockIdx.x;
    const int t = threadIdx.x;
    float* row = s + (size_t)b * L_;

    __shared__ float sm[4];
    __shared__ float sm2[4];

    float lmax = -1e30f;
    for (int l = t; l < L_; l += 256) lmax = fmaxf(lmax, row[l]);
    for (int off = 32; off > 0; off >>= 1) lmax = fmaxf(lmax, __shfl_down(lmax, off));
    if ((t & 63) == 0) sm[t >> 6] = lmax;
    __syncthreads();
    float gmax = fmaxf(fmaxf(sm[0], sm[1]), fmaxf(sm[2], sm[3]));

    float lsum = 0.f;
    for (int l = t; l < L_; l += 256) {
        float e = expf(row[l] - gmax);
        row[l] = e;
        lsum += e;
    }
    for (int off = 32; off > 0; off >>= 1) lsum += __shfl_down(lsum, off);
    if ((t & 63) == 0) sm2[t >> 6] = lsum;
    __syncthreads();
    float inv = 1.f / (sm2[0] + sm2[1] + sm2[2] + sm2[3]);
    for (int l = t; l < L_; l += 256) row[l] *= inv;
}

// ---------------------------------------------------------------------------
// Kernel 4: partial center_raw. grid B_*CRCH: b = bx>>4, chunk c = bx&15.
// ---------------------------------------------------------------------------
__global__ __launch_bounds__(512) void center_raw_kernel(
    const float* __restrict__ x, const float* __restrict__ attn,
    float* __restrict__ craw_p)
{
    const int b = blockIdx.x >> 4;
    const int c = blockIdx.x & 15;
    const int n = threadIdx.x;
    __shared__ float ash[CRL];
    const int l0 = c * CRL;
    if (n < CRL) ash[n] = attn[b * L_ + l0 + n];
    __syncthreads();
    const float* xb = x + ((size_t)b * L_ + l0) * N_;
    float acc = 0.f;
    #pragma unroll 3
    for (int l = 0; l < CRL; l++) acc += ash[l] * xb[(size_t)l * N_ + n];
    craw_p[(size_t)(b * CRCH + c) * N_ + n] = acc;
}

__device__ __forceinline__ float gelu_exact(float v) {
    return 0.5f * v * (1.0f + erff(v * 0.70710678118654752440f));
}

// ---------------------------------------------------------------------------
// Kernel 5: reduce partials + center MLP -> center. grid B_, 512 thr.
// ---------------------------------------------------------------------------
__global__ __launch_bounds__(512) void center_mlp_kernel(
    const float* __restrict__ craw_p,
    const float* __restrict__ Wc1, const float* __restrict__ bc1,
    const float* __restrict__ Wc2, const float* __restrict__ bc2,
    const float* __restrict__ Wcn, const float* __restrict__ bcn,
    float* __restrict__ center)
{
    const int b = blockIdx.x;
    const int t = threadIdx.x;
    const int col = t & 63;
    const int seg = t >> 6;
    __shared__ float cr[N_];
    __shared__ float psum[8][D_];
    __shared__ float h1[D_];
    __shared__ float h2[D_];

    {
        float acc = 0.f;
        #pragma unroll
        for (int c = 0; c < CRCH; ++c) acc += craw_p[(size_t)(b * CRCH + c) * N_ + t];
        cr[t] = acc;
    }
    __syncthreads();
    {
        float p = 0.f;
        #pragma unroll 8
        for (int m = seg * 64; m < seg * 64 + 64; ++m) p += cr[m] * Wc1[m * D_ + col];
        psum[seg][col] = p;
    }
    __syncthreads();
    if (t < D_) {
        float acc = bc1[t];
        #pragma unroll
        for (int s2 = 0; s2 < 8; ++s2) acc += psum[s2][t];
        h1[t] = gelu_exact(acc);
    }
    __syncthreads();
    if (t < D_) {
        float acc = bc2[t];
        #pragma unroll 8
        for (int j = 0; j < D_; j++) acc += h1[j] * Wc2[j * D_ + t];
        h2[t] = gelu_exact(acc);
    }
    __syncthreads();
    {
        float acc = bcn[t];
        #pragma unroll 8
        for (int j = 0; j < D_; j++) acc += h2[j] * Wcn[j * N_ + t];
        center[b * N_ + t] = acc;
    }
}

// ---------------------------------------------------------------------------
// Kernel 6: cg[b,n] = center[b]·Wg[512+.,n] + bg[n].
// ---------------------------------------------------------------------------
__global__ __launch_bounds__(512) void cg_kernel(
    const float* __restrict__ center, const float* __restrict__ Wg,
    const float* __restrict__ bg, float* __restrict__ cg)
{
    const int nc = blockIdx.x;
    const int b  = blockIdx.y;
    const int t  = threadIdx.x;
    const int col = nc * 64 + (t & 63);
    const int seg = t >> 6;
    __shared__ float cs[N_];
    __shared__ float psum[8][64];

    cs[t] = center[b * N_ + t];
    __syncthreads();
    {
        float p = 0.f;
        const float* wp = Wg + (size_t)(N_ + seg * 64) * N_ + col;
        #pragma unroll 8
        for (int m = 0; m < 64; ++m) { p += cs[seg * 64 + m] * wp[0]; wp += N_; }
        psum[seg][t & 63] = p;
    }
    __syncthreads();
    if (t < 64) {
        float acc = bg[nc * 64 + t];
        #pragma unroll
        for (int s2 = 0; s2 < 8; ++s2) acc += psum[s2][t];
        cg[b * N_ + nc * 64 + t] = acc;
    }
}

// ---------------------------------------------------------------------------
// Kernel 7: transpose+convert Wg-top / Wf to bf16 (N x K row-major)
// ---------------------------------------------------------------------------
__global__ __launch_bounds__(256) void convert_kernel(
    const float* __restrict__ Wg, const float* __restrict__ Wf,
    __hip_bfloat16* __restrict__ WgT, __hip_bfloat16* __restrict__ WfT)
{
    const int n = blockIdx.x & 511;
    const bool isf = blockIdx.x >= 512;
    const float* src = isf ? Wf : Wg;
    __hip_bfloat16* dst = isf ? WfT : WgT;
    for (int k = threadIdx.x; k < N_; k += 256)
        dst[n * N_ + k] = __float2bfloat16(src[(size_t)k * N_ + n]);
}

// ---------------------------------------------------------------------------
// GEMM core (m97 structure): C(128x128) = A(128x512) @ BT(128x512)^T.
// ---------------------------------------------------------------------------
#define GEMM_BODY(EPILOGUE)                                                    \
    __shared__ __hip_bfloat16 Ash[128 * 64];                                   \
    __shared__ __hip_bfloat16 Bsh[128 * 64];                                   \
    const int tid  = threadIdx.x;                                              \
    const int lane = tid & 63;                                                 \
    const int wv   = tid >> 6;                                                 \
    const int m32  = lane & 31;                                                \
    const int half = lane >> 5;                                                \
    const int wr   = wv >> 1;                                                  \
    const int wc   = wv & 1;                                                   \
    const int row0 = blockIdx.x * 128;                                         \
    const int n0   = blockIdx.y * 128;                                         \
    const int swz  = (lane & 7) ^ (lane >> 3);                                 \
    const int rln  = lane >> 3;                                                \
    f32x16 acc[2][2];                                                          \
    _Pragma("unroll") for (int i = 0; i < 2; i++)                              \
        _Pragma("unroll") for (int j = 0; j < 2; j++)                          \
            _Pragma("unroll") for (int e = 0; e < 16; e++) acc[i][j][e] = 0.f; \
    for (int step = 0; step < 8; ++step) {                                     \
        const int k0 = step * 64;                                              \
        const __hip_bfloat16* Ab = A  + (size_t)row0 * N_ + k0 + swz * 8;      \
        const __hip_bfloat16* Bb = BT + (size_t)n0   * N_ + k0 + swz * 8;      \
        __syncthreads();                                                       \
        _Pragma("unroll") for (int j = 0; j < 4; ++j) {                        \
            const int r = j * 32 + wv * 8 + rln;                               \
            const int lb = (j * 256 + wv * 64) * 8;                            \
            async_cp16(Ab + (size_t)r * N_, Ash + lb);                         \
            async_cp16(Bb + (size_t)r * N_, Bsh + lb);                         \
        }                                                                      \
        __syncthreads();                                                       \
        _Pragma("unroll") for (int ks = 0; ks < 4; ++ks) {                     \
            const int j0 = ks * 2 + half;                                      \
            bf16x8 a0 = frag_ld(Ash, wr * 64      + m32, j0);                  \
            bf16x8 a1 = frag_ld(Ash, wr * 64 + 32 + m32, j0);                  \
            bf16x8 b0 = frag_ld(Bsh, wc * 64      + m32, j0);                  \
            bf16x8 b1 = frag_ld(Bsh, wc * 64 + 32 + m32, j0);                  \
            acc[0][0] = __builtin_amdgcn_mfma_f32_32x32x16_bf16(a0, b0, acc[0][0], 0, 0, 0); \
            acc[0][1] = __builtin_amdgcn_mfma_f32_32x32x16_bf16(a0, b1, acc[0][1], 0, 0, 0); \
            acc[1][0] = __builtin_amdgcn_mfma_f32_32x32x16_bf16(a1, b0, acc[1][0], 0, 0, 0); \
            acc[1][1] = __builtin_amdgcn_mfma_f32_32x32x16_bf16(a1, b1, acc[1][1], 0, 0, 0); \
        }                                                                      \
    }                                                                          \
    _Pragma("unroll") for (int mi = 0; mi < 2; ++mi)                           \
        _Pragma("unroll") for (int ni = 0; ni < 2; ++ni)                       \
            _Pragma("unroll") for (int reg = 0; reg < 16; ++reg) {             \
                const int rg  = row0 + wr * 64 + mi * 32 +                     \
                                (reg & 3) + 8 * (reg >> 2) + 4 * half;         \
                const int col = n0 + wc * 64 + ni * 32 + m32;                  \
                const float aval = acc[mi][ni][reg];                           \
                EPILOGUE                                                       \
            }

// Kernel 8: gate GEMM; fused = sigmoid(ring@WgT^T + cg)*ring + (1-g)*center
__global__ __launch_bounds__(256) void gemm_gate_kernel(
    const __hip_bfloat16* __restrict__ A,
    const __hip_bfloat16* __restrict__ BT,
    const float* __restrict__ cg,
    const float* __restrict__ center,
    __hip_bfloat16* __restrict__ fused)
{
    GEMM_BODY({
        const int b = rg / L_;
        const float logit = aval + cg[b * N_ + col];
        const float g = 1.f / (1.f + expf(-logit));
        const float rv = __bfloat162float(A[(size_t)rg * N_ + col]);
        const float f = g * rv + (1.f - g) * center[b * N_ + col];
        fused[(size_t)rg * N_ + col] = __float2bfloat16(f);
    })
}

// Kernel 9: output GEMM; h = fused@WfT^T + bf + x  (fp32 -> d_out)
__global__ __launch_bounds__(256) void gemm_out_kernel(
    const __hip_bfloat16* __restrict__ A,
    const __hip_bfloat16* __restrict__ BT,
    const float* __restrict__ x,
    const float* __restrict__ bfv,
    float* __restrict__ out)
{
    GEMM_BODY({
        out[(size_t)rg * N_ + col] = aval + bfv[col] + x[(size_t)rg * N_ + col];
    })
}

// ---------------------------------------------------------------------------
// Kernel 10: LayerNorm, 4 rows/block, float4.
// ---------------------------------------------------------------------------
__global__ __launch_bounds__(512) void ln_kernel(
    float* __restrict__ out,
    const float* __restrict__ gamma, const float* __restrict__ beta)
{
    const int tid = threadIdx.x;
    const int r = tid >> 7;
    const int c = tid & 127;
    const int row = blockIdx.x * 4 + r;
    const int wid = tid >> 6;
    __shared__ float ls[8], lq[8];

    float4 v = ((const float4*)(out + (size_t)row * N_))[c];
    float sum = v.x + v.y + v.z + v.w;
    float sq  = v.x * v.x + v.y * v.y + v.z * v.z + v.w * v.w;
    for (int off = 32; off > 0; off >>= 1) {
        sum += __shfl_down(sum, off);
        sq  += __shfl_down(sq,  off);
    }
    if ((tid & 63) == 0) { ls[wid] = sum; lq[wid] = sq; }
    __syncthreads();
    const float S  = ls[2 * r] + ls[2 * r + 1];
    const float Q2 = lq[2 * r] + lq[2 * r + 1];
    const float mu  = S * (1.0f / N_);
    const float var = Q2 * (1.0f / N_) - mu * mu;
    const float inv = 1.0f / sqrtf(var + 1e-5f);
    const float4 g4 = ((const float4*)gamma)[c];
    const float4 b4 = ((const float4*)beta)[c];
    float4 o;
    o.x = (v.x - mu) * inv * g4.x + b4.x;
    o.y = (v.y - mu) * inv * g4.y + b4.y;
    o.z = (v.z - mu) * inv * g4.z + b4.z;
    o.w = (v.w - mu) * inv * g4.w + b4.w;
    ((float4*)(out + (size_t)row * N_))[c] = o;
}

// ---------------------------------------------------------------------------
extern "C" void kernel_launch(void* const* d_in, const int* in_sizes, int n_in,
                              void* d_out, int out_size, void* d_ws, size_t ws_size,
                              hipStream_t stream) {
    const float* x       = (const float*)d_in[0];
    const float* ve      = (const float*)d_in[1];
    const float* Wq      = (const float*)d_in[2];
    const float* bq      = (const float*)d_in[3];
    const float* Wk      = (const float*)d_in[4];
    const float* bk      = (const float*)d_in[5];
    const float* Wscore  = (const float*)d_in[6];
    const float* bscore  = (const float*)d_in[7];
    const float* Wc1     = (const float*)d_in[8];
    const float* bc1     = (const float*)d_in[9];
    const float* Wc2     = (const float*)d_in[10];
    const float* bc2     = (const float*)d_in[11];
    const float* Wcn     = (const float*)d_in[12];
    const float* bcn     = (const float*)d_in[13];
    const float* Wg      = (const float*)d_in[14];
    const float* bg      = (const float*)d_in[15];
    const float* Wf      = (const float*)d_in[16];
    const float* bf      = (const float*)d_in[17];
    const float* gamma   = (const float*)d_in[18];
    const float* beta    = (const float*)d_in[19];
    float* out = (float*)d_out;

    char* p = (char*)d_ws;
    float* ws_w    = (float*)p; p += N_ * TOPK_ * sizeof(float);
    int*   ws_idx  = (int*)p;   p += N_ * TOPK_ * sizeof(int);
    float* ws_s    = (float*)p; p += B_ * L_ * sizeof(float);
    float* ws_crp  = (float*)p; p += B_ * CRCH * N_ * sizeof(float);
    float* ws_cent = (float*)p; p += B_ * N_ * sizeof(float);
    float* ws_cg   = (float*)p; p += B_ * N_ * sizeof(float);
    float* ws_Q    = (float*)p; p += N_ * H_ * sizeof(float);
    float* ws_K    = (float*)p; p += N_ * H_ * sizeof(float);
    __hip_bfloat16* ws_ring  = (__hip_bfloat16*)p; p += (size_t)M_ * N_ * sizeof(__hip_bfloat16);
    __hip_bfloat16* ws_fused = (__hip_bfloat16*)p; p += (size_t)M_ * N_ * sizeof(__hip_bfloat16);
    __hip_bfloat16* ws_WgT   = (__hip_bfloat16*)p; p += (size_t)N_ * N_ * sizeof(__hip_bfloat16);
    __hip_bfloat16* ws_WfT   = (__hip_bfloat16*)p; p += (size_t)N_ * N_ * sizeof(__hip_bfloat16);

    convert_kernel<<<1024, 256, 0, stream>>>(Wg, Wf, ws_WgT, ws_WfT);
    qk_kernel<<<16, 512, 0, stream>>>(ve, Wq, bq, Wk, bk, ws_Q, ws_K);
    topk_kernel<<<N_, 64, 0, stream>>>(ws_Q, ws_K, ws_w, ws_idx);
    ring_kernel<<<M_ / RPB, 512, 0, stream>>>(x, ws_w, ws_idx, Wscore, bscore,
                                              ws_ring, ws_s);
    attn_softmax_kernel<<<B_, 256, 0, stream>>>(ws_s);
    center_raw_kernel<<<B_ * CRCH, 512, 0, stream>>>(x, ws_s, ws_crp);
    center_mlp_kernel<<<B_, 512, 0, stream>>>(ws_crp, Wc1, bc1, Wc2, bc2,
                                              Wcn, bcn, ws_cent);
    cg_kernel<<<dim3(8, B_), 512, 0, stream>>>(ws_cent, Wg, bg, ws_cg);
    dim3 ggrid(M_ / 128, N_ / 128);
    gemm_gate_kernel<<<ggrid, 256, 0, stream>>>(ws_ring, ws_WgT, ws_cg,
                                                ws_cent, ws_fused);
    gemm_out_kernel<<<ggrid, 256, 0, stream>>>(ws_fused, ws_WfT, x, bf, out);
    ln_kernel<<<M_ / 4, 512, 0, stream>>>(out, gamma, beta);
}